// Round 3
// baseline (1944.793 us; speedup 1.0000x reference)
//
#include <hip/hip_runtime.h>
#include <math.h>

typedef unsigned int uint;
typedef unsigned short ushort;

#define HWp 90000

__device__ __forceinline__ float bf2f(ushort u) { return __uint_as_float(((uint)u) << 16); }
__device__ __forceinline__ ushort f2bf(float f) {
    uint u = __float_as_uint(f);
    uint r = (u + 0x7FFFu + ((u >> 16) & 1u)) >> 16;
    return (ushort)r;
}
// order-preserving float<->uint for atomicMax
__device__ __forceinline__ uint enc(float f) {
    uint u = __float_as_uint(f);
    return (u & 0x80000000u) ? ~u : (u | 0x80000000u);
}
__device__ __forceinline__ float dec(uint k) {
    uint u = (k & 0x80000000u) ? (k ^ 0x80000000u) : ~k;
    return __uint_as_float(u);
}

// ---------------------------------------------------------------------------
// k_fuse_conv: conv3x3(cat(resize(x2),resize(x3),resize(x4)), 192->64) + bias
// writes raw (conv+bias) to preb, per-block (sum,sumsq) doubles to part.
// Tile: 8 rows x 64 cols, 512 threads = 64 px-groups(8px row-seg) x 8 oc-groups(8oc)
// ---------------------------------------------------------------------------
__global__ __launch_bounds__(512, 4) void k_fuse_conv(
    const float* __restrict__ x2, const float* __restrict__ x3, const float* __restrict__ x4,
    const float* __restrict__ Wf, const float* __restrict__ bfv,
    float* __restrict__ preb, double* __restrict__ part)
{
    __shared__ float lds_x[10 * 67];
    __shared__ float lds_w[576];
    __shared__ double red[16];
    const int tid = threadIdx.x;
    const int b = blockIdx.z;
    const int ty0 = blockIdx.y * 8;
    const int tx0 = blockIdx.x * 64;
    const int pxg = tid & 63, ocg = tid >> 6;
    const int r = pxg >> 3, cs = pxg & 7;
    const int oc0 = ocg * 8;
    const int y = ty0 + r;
    const int x0 = tx0 + cs * 8;

    float acc[8][8];
#pragma unroll
    for (int j = 0; j < 8; ++j)
#pragma unroll
        for (int o = 0; o < 8; ++o) acc[j][o] = 0.f;

    for (int c = 0; c < 192; ++c) {
        const int ssel = c >> 6;
        const float* src = (ssel == 0) ? x2 : (ssel == 1 ? x3 : x4);
        const int n = (ssel == 0) ? 75 : (ssel == 1 ? 38 : 19);
        const float scale = (float)n * (1.0f / 300.0f);
        const float* sp = src + (size_t)(b * 64 + (c & 63)) * n * n;
        for (int s = tid; s < 660; s += 512) {
            int ly = s / 66, lx = s - ly * 66;
            int gy = ty0 + ly - 1, gx = tx0 + lx - 1;
            float v = 0.f;
            if ((uint)gy < 300u && (uint)gx < 300u) {
                float fy = ((float)gy + 0.5f) * scale - 0.5f;
                float fx = ((float)gx + 0.5f) * scale - 0.5f;
                int iy = (int)floorf(fy), ix = (int)floorf(fx);
                float ay = fy - (float)iy, ax = fx - (float)ix;
                int y0c = min(max(iy, 0), n - 1), y1c = min(iy + 1, n - 1);
                int x0c = min(max(ix, 0), n - 1), x1c = min(ix + 1, n - 1);
                const float* r0 = sp + y0c * n;
                const float* r1 = sp + y1c * n;
                float v0 = (1.f - ax) * r0[x0c] + ax * r0[x1c];
                float v1 = (1.f - ax) * r1[x0c] + ax * r1[x1c];
                v = (1.f - ay) * v0 + ay * v1;
            }
            lds_x[ly * 67 + lx] = v;
        }
        for (int s = tid; s < 576; s += 512) {
            int oc = s & 63, tap = s >> 6;
            lds_w[tap * 64 + oc] = Wf[(size_t)oc * (192 * 9) + c * 9 + tap];
        }
        __syncthreads();
#pragma unroll
        for (int ky = 0; ky < 3; ++ky) {
            float xr[10];
            const float* xp = &lds_x[(r + ky) * 67 + cs * 8];
#pragma unroll
            for (int t = 0; t < 10; ++t) xr[t] = xp[t];
#pragma unroll
            for (int kx = 0; kx < 3; ++kx) {
                const float* wp = &lds_w[(ky * 3 + kx) * 64 + oc0];
                float wv[8];
#pragma unroll
                for (int o = 0; o < 8; ++o) wv[o] = wp[o];
#pragma unroll
                for (int j = 0; j < 8; ++j)
#pragma unroll
                    for (int o = 0; o < 8; ++o)
                        acc[j][o] = fmaf(xr[kx + j], wv[o], acc[j][o]);
            }
        }
        __syncthreads();
    }
    // epilogue: bias, store raw, partial stats
    float s = 0.f, ss = 0.f;
    if (y < 300) {
#pragma unroll
        for (int o = 0; o < 8; ++o) {
            float bia = bfv[oc0 + o];
            float* op = preb + ((size_t)(b * 64 + oc0 + o)) * HWp + y * 300 + x0;
            if (x0 + 7 < 300) {
                float4 u, vv;
                u.x = acc[0][o] + bia; u.y = acc[1][o] + bia; u.z = acc[2][o] + bia; u.w = acc[3][o] + bia;
                vv.x = acc[4][o] + bia; vv.y = acc[5][o] + bia; vv.z = acc[6][o] + bia; vv.w = acc[7][o] + bia;
                *(float4*)op = u;
                *(float4*)(op + 4) = vv;
                s += u.x + u.y + u.z + u.w + vv.x + vv.y + vv.z + vv.w;
                ss += u.x * u.x + u.y * u.y + u.z * u.z + u.w * u.w + vv.x * vv.x + vv.y * vv.y + vv.z * vv.z + vv.w * vv.w;
            } else {
#pragma unroll
                for (int j = 0; j < 8; ++j) {
                    if (x0 + j < 300) {
                        float t = acc[j][o] + bia;
                        op[j] = t; s += t; ss += t * t;
                    }
                }
            }
        }
    }
    double ds = s, dss = ss;
    for (int off = 32; off; off >>= 1) { ds += __shfl_down(ds, off); dss += __shfl_down(dss, off); }
    const int wid = tid >> 6, lane = tid & 63;
    if (lane == 0) { red[wid * 2] = ds; red[wid * 2 + 1] = dss; }
    __syncthreads();
    if (tid == 0) {
        double S = 0, SS = 0;
#pragma unroll
        for (int w = 0; w < 8; ++w) { S += red[2 * w]; SS += red[2 * w + 1]; }
        int blin = (blockIdx.z * 38 + blockIdx.y) * 5 + blockIdx.x;
        part[2 * blin] = S; part[2 * blin + 1] = SS;
    }
}

// ---------------------------------------------------------------------------
// k_fuse0_conv: conv3x3(base, 64->64) + bias -> bf16 [b][y][x][c] + stats
// ---------------------------------------------------------------------------
__global__ __launch_bounds__(512, 4) void k_fuse0_conv(
    const float* __restrict__ basep, const float* __restrict__ W0, const float* __restrict__ b0,
    ushort* __restrict__ f0c, double* __restrict__ part)
{
    __shared__ float lds_x[10 * 67];
    __shared__ float lds_w[576];
    __shared__ double red[16];
    const int tid = threadIdx.x;
    const int b = blockIdx.z;
    const int ty0 = blockIdx.y * 8;
    const int tx0 = blockIdx.x * 64;
    const int pxg = tid & 63, ocg = tid >> 6;
    const int r = pxg >> 3, cs = pxg & 7;
    const int oc0 = ocg * 8;
    const int y = ty0 + r;
    const int x0 = tx0 + cs * 8;

    float acc[8][8];
#pragma unroll
    for (int j = 0; j < 8; ++j)
#pragma unroll
        for (int o = 0; o < 8; ++o) acc[j][o] = 0.f;

    for (int c = 0; c < 64; ++c) {
        const float* sp = basep + (size_t)(b * 64 + c) * HWp;
        for (int s = tid; s < 660; s += 512) {
            int ly = s / 66, lx = s - ly * 66;
            int gy = ty0 + ly - 1, gx = tx0 + lx - 1;
            float v = 0.f;
            if ((uint)gy < 300u && (uint)gx < 300u) v = sp[gy * 300 + gx];
            lds_x[ly * 67 + lx] = v;
        }
        for (int s = tid; s < 576; s += 512) {
            int oc = s & 63, tap = s >> 6;
            lds_w[tap * 64 + oc] = W0[(size_t)oc * 576 + c * 9 + tap];
        }
        __syncthreads();
#pragma unroll
        for (int ky = 0; ky < 3; ++ky) {
            float xr[10];
            const float* xp = &lds_x[(r + ky) * 67 + cs * 8];
#pragma unroll
            for (int t = 0; t < 10; ++t) xr[t] = xp[t];
#pragma unroll
            for (int kx = 0; kx < 3; ++kx) {
                const float* wp = &lds_w[(ky * 3 + kx) * 64 + oc0];
                float wv[8];
#pragma unroll
                for (int o = 0; o < 8; ++o) wv[o] = wp[o];
#pragma unroll
                for (int j = 0; j < 8; ++j)
#pragma unroll
                    for (int o = 0; o < 8; ++o)
                        acc[j][o] = fmaf(xr[kx + j], wv[o], acc[j][o]);
            }
        }
        __syncthreads();
    }
    float s = 0.f, ss = 0.f;
    if (y < 300) {
        float bia[8];
#pragma unroll
        for (int o = 0; o < 8; ++o) bia[o] = b0[oc0 + o];
#pragma unroll
        for (int j = 0; j < 8; ++j) {
            int x = x0 + j;
            if (x < 300) {
                float t[8];
#pragma unroll
                for (int o = 0; o < 8; ++o) { t[o] = acc[j][o] + bia[o]; s += t[o]; ss += t[o] * t[o]; }
                uint4 pk;
                pk.x = (uint)f2bf(t[0]) | ((uint)f2bf(t[1]) << 16);
                pk.y = (uint)f2bf(t[2]) | ((uint)f2bf(t[3]) << 16);
                pk.z = (uint)f2bf(t[4]) | ((uint)f2bf(t[5]) << 16);
                pk.w = (uint)f2bf(t[6]) | ((uint)f2bf(t[7]) << 16);
                *(uint4*)(f0c + (((size_t)b * 300 + y) * 300 + x) * 64 + oc0) = pk;
            }
        }
    }
    double ds = s, dss = ss;
    for (int off = 32; off; off >>= 1) { ds += __shfl_down(ds, off); dss += __shfl_down(dss, off); }
    const int wid = tid >> 6, lane = tid & 63;
    if (lane == 0) { red[wid * 2] = ds; red[wid * 2 + 1] = dss; }
    __syncthreads();
    if (tid == 0) {
        double S = 0, SS = 0;
#pragma unroll
        for (int w = 0; w < 8; ++w) { S += red[2 * w]; SS += red[2 * w + 1]; }
        int blin = (blockIdx.z * 38 + blockIdx.y) * 5 + blockIdx.x;
        part[2 * blin] = S; part[2 * blin + 1] = SS;
    }
}

// reduce (sum,sumsq) partials -> (mu, rsqrt(var+eps))
__global__ __launch_bounds__(64) void k_redstats(const double* __restrict__ part, int cnt,
                                                 double invN, float* __restrict__ stats)
{
    int b = blockIdx.x, t = threadIdx.x;
    double s = 0, ss = 0;
    for (int i = t; i < cnt; i += 64) { s += part[2 * (b * cnt + i)]; ss += part[2 * (b * cnt + i) + 1]; }
    for (int off = 32; off; off >>= 1) { s += __shfl_down(s, off); ss += __shfl_down(ss, off); }
    if (t == 0) {
        double mu = s * invN;
        double var = ss * invN - mu * mu;
        stats[2 * b] = (float)mu;
        stats[2 * b + 1] = (float)(1.0 / sqrt(var + 1e-5));
    }
}

__global__ __launch_bounds__(64) void k_redmean(const double* __restrict__ part, int cnt,
                                                double invN, float* __restrict__ out)
{
    int b = blockIdx.x, t = threadIdx.x;
    double s = 0;
    for (int i = t; i < cnt; i += 64) s += part[b * cnt + i];
    for (int off = 32; off; off >>= 1) s += __shfl_down(s, off);
    if (t == 0) out[b] = (float)(s * invN);
}

// GN+ReLU in place (preb -> base) + bcg 1x1 conv + sigmoid + per-block bcg sums
__global__ __launch_bounds__(256) void k_finalize(
    float* __restrict__ basep, float* __restrict__ bcg_out,
    const float* __restrict__ fg, const float* __restrict__ fbe,
    const float* __restrict__ wb, const float* __restrict__ bb,
    const float* __restrict__ fstats, double* __restrict__ bcgpart)
{
    const int b = blockIdx.y;
    const int idx = blockIdx.x * 256 + threadIdx.x;
    float lsum = 0.f;
    if (idx < 22500) {
        const int p4 = idx * 4;
        const float mu = fstats[b * 2], rs = fstats[b * 2 + 1];
        float4 acc = make_float4(0.f, 0.f, 0.f, 0.f);
        for (int c = 0; c < 64; ++c) {
            float* ptr = basep + ((size_t)(b * 64 + c)) * HWp + p4;
            float4 v = *(float4*)ptr;
            const float g = fg[c], be = fbe[c];
            float4 t;
            t.x = fmaxf((v.x - mu) * rs * g + be, 0.f);
            t.y = fmaxf((v.y - mu) * rs * g + be, 0.f);
            t.z = fmaxf((v.z - mu) * rs * g + be, 0.f);
            t.w = fmaxf((v.w - mu) * rs * g + be, 0.f);
            *(float4*)ptr = t;
            const float wc = wb[c];
            acc.x = fmaf(wc, t.x, acc.x);
            acc.y = fmaf(wc, t.y, acc.y);
            acc.z = fmaf(wc, t.z, acc.z);
            acc.w = fmaf(wc, t.w, acc.w);
        }
        const float bz = bb[0];
        float4 sg;
        sg.x = 1.f / (1.f + expf(-(acc.x + bz)));
        sg.y = 1.f / (1.f + expf(-(acc.y + bz)));
        sg.z = 1.f / (1.f + expf(-(acc.z + bz)));
        sg.w = 1.f / (1.f + expf(-(acc.w + bz)));
        *(float4*)(bcg_out + (size_t)b * HWp + p4) = sg;
        lsum = sg.x + sg.y + sg.z + sg.w;
    }
    double d = lsum;
    for (int off = 32; off; off >>= 1) d += __shfl_down(d, off);
    __shared__ double rr[4];
    int wid = threadIdx.x >> 6, lane = threadIdx.x & 63;
    if (lane == 0) rr[wid] = d;
    __syncthreads();
    if (threadIdx.x == 0) bcgpart[b * 88 + blockIdx.x] = rr[0] + rr[1] + rr[2] + rr[3];
}

// fdm_m = fdm * (bcg > mean); pooled = 10x10 window max of fdm_m
__global__ __launch_bounds__(128) void k_maskpool(
    const float* __restrict__ fdm, const float* __restrict__ bcg,
    const float* __restrict__ bcgmean, float* __restrict__ fdm_m, float* __restrict__ pooled)
{
    const int cell = blockIdx.x;
    const int b = blockIdx.y;
    const int t = threadIdx.x;
    const int cy = cell / 30, cx = cell - cy * 30;
    float m = -INFINITY;
    if (t < 100) {
        int yy = cy * 10 + t / 10, xx = cx * 10 + t % 10;
        size_t p = (size_t)b * HWp + yy * 300 + xx;
        float v = (bcg[p] > bcgmean[b]) ? fdm[p] : 0.f;
        fdm_m[p] = v;
        m = v;
    }
    for (int off = 32; off; off >>= 1) m = fmaxf(m, __shfl_down(m, off));
    __shared__ float rr[2];
    if ((t & 63) == 0) rr[t >> 6] = m;
    __syncthreads();
    if (t == 0) pooled[b * 900 + cell] = fmaxf(rr[0], rr[1]);
}

// vertical antialiased triangle downsample of relu(GN(f0conv)) : 300 -> 30 rows
__global__ __launch_bounds__(256) void k_vert(
    const ushort* __restrict__ f0c, const float* __restrict__ g0, const float* __restrict__ be0,
    const float* __restrict__ f0stats, float* __restrict__ vtmp)
{
    const int idx = blockIdx.x * 256 + threadIdx.x;
    if (idx >= 4 * 30 * 300 * 64) return;
    const int c = idx & 63;
    int rest = idx >> 6;
    const int x = rest % 300; rest /= 300;
    const int j = rest % 30;
    const int b = rest / 30;
    const float mu = f0stats[2 * b], rs = f0stats[2 * b + 1];
    const float gg = g0[c], bb = be0[c];
    const int ylo = max(0, 10 * j - 5), yhi = min(299, 10 * j + 14);
    const float centre = (float)(10 * j) + 4.5f;
    float acc = 0.f, wsum = 0.f;
    for (int yy = ylo; yy <= yhi; ++yy) {
        float w = 1.0f - fabsf((float)yy - centre) * 0.1f;
        float v = bf2f(f0c[(((size_t)b * 300 + yy) * 300 + x) * 64 + c]);
        float t = fmaxf((v - mu) * rs * gg + bb, 0.f);
        acc = fmaf(w, t, acc);
        wsum += w;
    }
    vtmp[idx] = acc / wsum;
}

// horizontal pass: 300 -> 30 cols; emit B = nl30, A = pooled*nl30, layout [b][sp][c]
__global__ __launch_bounds__(256) void k_horiz(
    const float* __restrict__ vtmp, const float* __restrict__ pooled,
    float* __restrict__ A, float* __restrict__ Bm)
{
    const int idx = blockIdx.x * 256 + threadIdx.x;
    if (idx >= 4 * 30 * 30 * 64) return;
    const int c = idx & 63;
    int rest = idx >> 6;
    const int i = rest % 30; rest /= 30;
    const int j = rest % 30;
    const int b = rest / 30;
    const int xlo = max(0, 10 * i - 5), xhi = min(299, 10 * i + 14);
    const float centre = (float)(10 * i) + 4.5f;
    float acc = 0.f, wsum = 0.f;
    for (int xx = xlo; xx <= xhi; ++xx) {
        float w = 1.0f - fabsf((float)xx - centre) * 0.1f;
        acc = fmaf(w, vtmp[(((size_t)b * 30 + j) * 300 + xx) * 64 + c], acc);
        wsum += w;
    }
    float nl30 = acc / wsum;
    Bm[idx] = nl30;
    A[idx] = pooled[b * 900 + j * 30 + i] * nl30;
}

// nl[b,i] = max_j sum_c A[b,i,c]*B[b,j,c]  (atomicMax on encoded key)
__global__ __launch_bounds__(256) void k_nl(
    const float* __restrict__ A, const float* __restrict__ Bm, uint* __restrict__ nlkey)
{
    __shared__ float lb[75 * 64];
    const int b = blockIdx.z;
    const int j0 = blockIdx.x * 75;
    const int i1 = blockIdx.y * 512 + threadIdx.x;
    const int i2 = i1 + 256;
    for (int s = threadIdx.x; s < 75 * 64; s += 256)
        lb[s] = Bm[(size_t)(b * 900 + j0) * 64 + s];
    __syncthreads();
    const bool v1 = i1 < 900, v2 = i2 < 900;
    float a1[64], a2[64];
    const float* A1 = A + (size_t)(b * 900 + i1) * 64;
    const float* A2 = A + (size_t)(b * 900 + i2) * 64;
#pragma unroll
    for (int c = 0; c < 64; ++c) { a1[c] = v1 ? A1[c] : 0.f; a2[c] = v2 ? A2[c] : 0.f; }
    float m1 = -INFINITY, m2 = -INFINITY;
    for (int jj = 0; jj < 75; ++jj) {
        const float* bp = lb + jj * 64;
        float d1 = 0.f, d2 = 0.f;
#pragma unroll
        for (int c = 0; c < 64; ++c) { float bv = bp[c]; d1 = fmaf(a1[c], bv, d1); d2 = fmaf(a2[c], bv, d2); }
        m1 = fmaxf(m1, d1); m2 = fmaxf(m2, d2);
    }
    if (v1) atomicMax(&nlkey[b * 900 + i1], enc(m1));
    if (v2) atomicMax(&nlkey[b * 900 + i2], enc(m2));
}

// base2 = upsample(nl,30->300) * base; sup = 1x1 conv of base2
__global__ __launch_bounds__(256) void k_base2_sup(
    const float* __restrict__ basep, const uint* __restrict__ nlkey,
    const float* __restrict__ wsup, const float* __restrict__ bsup,
    float* __restrict__ out_b2, float* __restrict__ out_sup)
{
    const int b = blockIdx.y;
    const int idx = blockIdx.x * 256 + threadIdx.x;
    if (idx >= 22500) return;
    const int p4 = idx * 4;
    const int yy = p4 / 300, xx = p4 - yy * 300;
    const uint* nk = nlkey + b * 900;
    float cyf = ((float)yy + 0.5f) * 0.1f - 0.5f;
    int iy = (int)floorf(cyf);
    float ay = cyf - (float)iy;
    int jy0 = min(max(iy, 0), 29), jy1 = min(iy + 1, 29);
    float e[4];
#pragma unroll
    for (int k = 0; k < 4; ++k) {
        float cxf = ((float)(xx + k) + 0.5f) * 0.1f - 0.5f;
        int ix = (int)floorf(cxf);
        float ax = cxf - (float)ix;
        int jx0 = min(max(ix, 0), 29), jx1 = min(ix + 1, 29);
        float n00 = dec(nk[jy0 * 30 + jx0]), n01 = dec(nk[jy0 * 30 + jx1]);
        float n10 = dec(nk[jy1 * 30 + jx0]), n11 = dec(nk[jy1 * 30 + jx1]);
        e[k] = (1.f - ay) * ((1.f - ax) * n00 + ax * n01) + ay * ((1.f - ax) * n10 + ax * n11);
    }
    float4 sacc = make_float4(0.f, 0.f, 0.f, 0.f);
    for (int c = 0; c < 64; ++c) {
        size_t off = ((size_t)(b * 64 + c)) * HWp + p4;
        float4 v = *(const float4*)(basep + off);
        float4 t;
        t.x = v.x * e[0]; t.y = v.y * e[1]; t.z = v.z * e[2]; t.w = v.w * e[3];
        *(float4*)(out_b2 + off) = t;
        const float wc = wsup[c];
        sacc.x = fmaf(wc, t.x, sacc.x);
        sacc.y = fmaf(wc, t.y, sacc.y);
        sacc.z = fmaf(wc, t.z, sacc.z);
        sacc.w = fmaf(wc, t.w, sacc.w);
    }
    const float bz = bsup[0];
    float4 so;
    so.x = sacc.x + bz; so.y = sacc.y + bz; so.z = sacc.z + bz; so.w = sacc.w + bz;
    *(float4*)(out_sup + (size_t)b * HWp + p4) = so;
}

// ---------------------------------------------------------------------------
extern "C" void kernel_launch(void* const* d_in, const int* in_sizes, int n_in,
                              void* d_out, int out_size, void* d_ws, size_t ws_size,
                              hipStream_t stream)
{
    (void)in_sizes; (void)n_in; (void)out_size; (void)ws_size;
    const float* fdm     = (const float*)d_in[0];
    const float* x2      = (const float*)d_in[3];
    const float* x3      = (const float*)d_in[4];
    const float* x4      = (const float*)d_in[5];
    const float* fuse_W  = (const float*)d_in[6];
    const float* fuse_b  = (const float*)d_in[7];
    const float* fuse_g  = (const float*)d_in[8];
    const float* fuse_be = (const float*)d_in[9];
    const float* bcg_W   = (const float*)d_in[10];
    const float* bcg_b   = (const float*)d_in[11];
    const float* f0_W    = (const float*)d_in[12];
    const float* f0_b    = (const float*)d_in[13];
    const float* f0_g    = (const float*)d_in[14];
    const float* f0_be   = (const float*)d_in[15];
    const float* sup_W   = (const float*)d_in[16];
    const float* sup_b   = (const float*)d_in[17];

    // workspace layout
    char* ws = (char*)d_ws;
    float*  basep    = (float*)ws;                                   // 23,040,000 f32 (preb -> base in place)
    ushort* f0c      = (ushort*)(ws + 92160000);                     // 23,040,000 bf16
    double* fusepart = (double*)(ws + 92160000 + 46080000);          // 1520 dbl
    double* f0part   = fusepart + 1520;                              // 1520 dbl
    double* bcgpart  = f0part + 1520;                                // 352 dbl
    float*  fext     = (float*)(bcgpart + 352);
    float*  fstats   = fext;            // 8
    float*  f0stats  = fext + 8;        // 8
    float*  bcgmean  = fext + 16;       // 4
    float*  pooled   = fext + 32;       // 3600
    float*  Abuf     = fext + 4000;     // 230400
    float*  Bbuf     = fext + 234400;   // 230400
    float*  vtmp     = fext + 464800;   // 2,304,000
    uint*   nlkey    = (uint*)(fext + 2768800); // 3600

    float* o_fdm  = (float*)d_out;
    float* o_bcg  = o_fdm + 360000;
    float* o_b2   = o_fdm + 720000;
    float* o_sup  = o_fdm + 23760000;

    k_fuse_conv<<<dim3(5, 38, 4), 512, 0, stream>>>(x2, x3, x4, fuse_W, fuse_b, basep, fusepart);
    k_redstats<<<4, 64, 0, stream>>>(fusepart, 190, 1.0 / 5760000.0, fstats);
    k_finalize<<<dim3(88, 4), 256, 0, stream>>>(basep, o_bcg, fuse_g, fuse_be, bcg_W, bcg_b, fstats, bcgpart);
    k_redmean<<<4, 64, 0, stream>>>(bcgpart, 88, 1.0 / 90000.0, bcgmean);
    k_maskpool<<<dim3(900, 4), 128, 0, stream>>>(fdm, o_bcg, bcgmean, o_fdm, pooled);
    k_fuse0_conv<<<dim3(5, 38, 4), 512, 0, stream>>>(basep, f0_W, f0_b, f0c, f0part);
    k_redstats<<<4, 64, 0, stream>>>(f0part, 190, 1.0 / 5760000.0, f0stats);
    k_vert<<<9000, 256, 0, stream>>>(f0c, f0_g, f0_be, f0stats, vtmp);
    k_horiz<<<900, 256, 0, stream>>>(vtmp, pooled, Abuf, Bbuf);
    hipMemsetAsync(nlkey, 0, 3600 * sizeof(uint), stream);
    k_nl<<<dim3(12, 2, 4), 256, 0, stream>>>(Abuf, Bbuf, nlkey);
    k_base2_sup<<<dim3(88, 4), 256, 0, stream>>>(basep, nlkey, sup_W, sup_b, o_b2, o_sup);
}

// Round 5
// 1690.837 us; speedup vs baseline: 1.1502x; 1.1502x over previous
//
#include <hip/hip_runtime.h>
#include <math.h>

typedef unsigned int uint;
typedef unsigned short ushort;
typedef __attribute__((ext_vector_type(8))) short bf16x8;
typedef __attribute__((ext_vector_type(4))) float f32x4;

#define HWp 90000

__device__ __forceinline__ float bf2f(ushort u) { return __uint_as_float(((uint)u) << 16); }
__device__ __forceinline__ ushort f2bf(float f) {
    uint u = __float_as_uint(f);
    uint r = (u + 0x7FFFu + ((u >> 16) & 1u)) >> 16;
    return (ushort)r;
}
__device__ __forceinline__ uint enc(float f) {
    uint u = __float_as_uint(f);
    return (u & 0x80000000u) ? ~u : (u | 0x80000000u);
}
__device__ __forceinline__ float dec(uint k) {
    uint u = (k & 0x80000000u) ? (k ^ 0x80000000u) : ~k;
    return __uint_as_float(u);
}

// ---------------------------------------------------------------------------
// weight repacks (run every call; tiny)
// Wre[c][tap][oc] f32  <- fuse_W [oc][c][tap]
__global__ __launch_bounds__(256) void k_repack_fuse(const float* __restrict__ Wf, float* __restrict__ Wre) {
    int i = blockIdx.x * 256 + threadIdx.x;       // 192*9*64 = 110592
    if (i >= 110592) return;
    int oc = i & 63; int rest = i >> 6; int tap = rest % 9; int c = rest / 9;
    Wre[i] = Wf[(size_t)oc * 1728 + c * 9 + tap];
}
// Wfrag[tap][kstep][octile][lane][j] bf16 <- fuse0_W [oc][c][tap]
// lane l: oc = octile*16 + (l&15), c = kstep*32 + (l>>4)*8 + j
__global__ __launch_bounds__(256) void k_repack_f0(const float* __restrict__ W0, ushort* __restrict__ Wfrag) {
    int i = blockIdx.x * 256 + threadIdx.x;       // 9*2*4*64*8 = 36864
    if (i >= 36864) return;
    int j = i & 7; int l = (i >> 3) & 63; int octile = (i >> 9) & 3;
    int kstep = (i >> 11) & 1; int tap = i >> 12;
    int oc = octile * 16 + (l & 15);
    int c  = kstep * 32 + (l >> 4) * 8 + j;
    Wfrag[i] = f2bf(W0[(size_t)oc * 576 + c * 9 + tap]);
}

// ---------------------------------------------------------------------------
// k_fuse_conv: conv3x3(cat(resize(x2),resize(x3),resize(x4)), 192->64) + bias
// f32 VALU (mask path must stay f32-exact). Optimizations vs round 3:
//  - bilinear coord tables computed once per block (not per channel)
//  - weights via wave-uniform scalar loads from repacked Wre (no lds_w, no barrier)
//  - 2 channels per stage -> 192 barriers instead of 384
// ---------------------------------------------------------------------------
__global__ __launch_bounds__(512, 4) void k_fuse_conv(
    const float* __restrict__ x2, const float* __restrict__ x3, const float* __restrict__ x4,
    const float* __restrict__ Wre, const float* __restrict__ bfv,
    float* __restrict__ preb, double* __restrict__ part)
{
    __shared__ float lds_x[2][10 * 67];
    __shared__ int   t_y0[30], t_y1[30];
    __shared__ float t_wy[30];
    __shared__ int   t_x0[198], t_x1[198];
    __shared__ float t_wx[198];
    __shared__ double red[16];
    const int tid = threadIdx.x;
    const int b = blockIdx.z;
    const int ty0 = blockIdx.y * 8;
    const int tx0 = blockIdx.x * 64;
    const int pxg = tid & 63, ocg = tid >> 6;
    const int r = pxg >> 3, cs = pxg & 7;
    const int oc0 = __builtin_amdgcn_readfirstlane(ocg << 3);
    const int y = ty0 + r;
    const int x0 = tx0 + cs * 8;

    // coordinate tables: 3 sources x (10 rows + 66 cols)
    for (int i = tid; i < 228; i += 512) {
        int s = i / 76, k = i - s * 76;
        int n = (s == 0) ? 75 : (s == 1 ? 38 : 19);
        float scale = (float)n * (1.0f / 300.0f);
        if (k < 10) {
            int gy = ty0 + k - 1;
            float fy = ((float)gy + 0.5f) * scale - 0.5f;
            float fl = floorf(fy); int iy = (int)fl; float ay = fy - fl;
            int a0 = min(max(iy, 0), n - 1), a1 = min(iy + 1, n - 1);
            t_y0[s * 10 + k] = a0 * n; t_y1[s * 10 + k] = a1 * n; t_wy[s * 10 + k] = ay;
        } else {
            int j = k - 10;
            int gx = tx0 + j - 1;
            float fx = ((float)gx + 0.5f) * scale - 0.5f;
            float fl = floorf(fx); int ix = (int)fl; float ax = fx - fl;
            int a0 = min(max(ix, 0), n - 1), a1 = min(ix + 1, n - 1);
            t_x0[s * 66 + j] = a0; t_x1[s * 66 + j] = a1; t_wx[s * 66 + j] = ax;
        }
    }
    __syncthreads();

    float acc[8][8];
#pragma unroll
    for (int j = 0; j < 8; ++j)
#pragma unroll
        for (int o = 0; o < 8; ++o) acc[j][o] = 0.f;

    for (int c = 0; c < 192; c += 2) {
        const int ssel = c >> 6;
        const float* src = (ssel == 0) ? x2 : (ssel == 1 ? x3 : x4);
        const int n = (ssel == 0) ? 75 : (ssel == 1 ? 38 : 19);
        const float* sp0 = src + (size_t)(b * 64 + (c & 63)) * n * n;
        const float* sp1 = sp0 + n * n;
        const int* py0 = t_y0 + ssel * 10; const int* py1 = t_y1 + ssel * 10;
        const float* pwy = t_wy + ssel * 10;
        const int* px0 = t_x0 + ssel * 66; const int* px1 = t_x1 + ssel * 66;
        const float* pwx = t_wx + ssel * 66;
        for (int s = tid; s < 1320; s += 512) {
            int ch = (s >= 660) ? 1 : 0;
            int idx = s - (ch ? 660 : 0);
            int ly = idx / 66, lx = idx - ly * 66;
            float v = 0.f;
            int gy = ty0 + ly - 1, gx = tx0 + lx - 1;
            if ((uint)gy < 300u && (uint)gx < 300u) {
                const float* sp = ch ? sp1 : sp0;
                int r0 = py0[ly], r1 = py1[ly]; float fy = pwy[ly];
                int c0 = px0[lx], c1 = px1[lx]; float fx = pwx[lx];
                float v00 = sp[r0 + c0], v01 = sp[r0 + c1];
                float v10 = sp[r1 + c0], v11 = sp[r1 + c1];
                float va = (1.f - fx) * v00 + fx * v01;
                float vb = (1.f - fx) * v10 + fx * v11;
                v = (1.f - fy) * va + fy * vb;
            }
            lds_x[ch][ly * 67 + lx] = v;
        }
        __syncthreads();
        const float* sw = Wre + (size_t)c * 576 + oc0;   // [c][tap][oc], uniform per wave
#pragma unroll
        for (int ky = 0; ky < 3; ++ky) {
            float xa[10], xb[10];
            const float* xpa = &lds_x[0][(r + ky) * 67 + cs * 8];
            const float* xpb = &lds_x[1][(r + ky) * 67 + cs * 8];
#pragma unroll
            for (int t = 0; t < 10; ++t) { xa[t] = xpa[t]; xb[t] = xpb[t]; }
#pragma unroll
            for (int kx = 0; kx < 3; ++kx) {
                const float* w0 = sw + (ky * 3 + kx) * 64;
#pragma unroll
                for (int o = 0; o < 8; ++o) {
                    float wa = w0[o], wb = w0[576 + o];
#pragma unroll
                    for (int j = 0; j < 8; ++j)
                        acc[j][o] = fmaf(xa[kx + j], wa, fmaf(xb[kx + j], wb, acc[j][o]));
                }
            }
        }
        __syncthreads();
    }
    // epilogue: bias, store raw, partial stats (identical to round 3)
    float s = 0.f, ss = 0.f;
    if (y < 300) {
#pragma unroll
        for (int o = 0; o < 8; ++o) {
            float bia = bfv[oc0 + o];
            float* op = preb + ((size_t)(b * 64 + oc0 + o)) * HWp + y * 300 + x0;
            if (x0 + 7 < 300) {
                float4 u, vv;
                u.x = acc[0][o] + bia; u.y = acc[1][o] + bia; u.z = acc[2][o] + bia; u.w = acc[3][o] + bia;
                vv.x = acc[4][o] + bia; vv.y = acc[5][o] + bia; vv.z = acc[6][o] + bia; vv.w = acc[7][o] + bia;
                *(float4*)op = u;
                *(float4*)(op + 4) = vv;
                s += u.x + u.y + u.z + u.w + vv.x + vv.y + vv.z + vv.w;
                ss += u.x * u.x + u.y * u.y + u.z * u.z + u.w * u.w + vv.x * vv.x + vv.y * vv.y + vv.z * vv.z + vv.w * vv.w;
            } else {
#pragma unroll
                for (int j = 0; j < 8; ++j) {
                    if (x0 + j < 300) {
                        float t = acc[j][o] + bia;
                        op[j] = t; s += t; ss += t * t;
                    }
                }
            }
        }
    }
    double ds = s, dss = ss;
    for (int off = 32; off; off >>= 1) { ds += __shfl_down(ds, off); dss += __shfl_down(dss, off); }
    const int wid = tid >> 6, lane = tid & 63;
    if (lane == 0) { red[wid * 2] = ds; red[wid * 2 + 1] = dss; }
    __syncthreads();
    if (tid == 0) {
        double S = 0, SS = 0;
#pragma unroll
        for (int w = 0; w < 8; ++w) { S += red[2 * w]; SS += red[2 * w + 1]; }
        int blin = (blockIdx.z * 38 + blockIdx.y) * 5 + blockIdx.x;
        part[2 * blin] = S; part[2 * blin + 1] = SS;
    }
}

// ---------------------------------------------------------------------------
// k_fuse0_conv (MFMA): conv3x3(base, 64->64) + bias -> bf16 [b][y][x][c] + stats
// 256 thr = 4 waves; tile 4 rows x 16 cols; wave w owns row w, all 64 oc.
// A: LDS bf16 [patch_px][64c], 16B-slot XOR swizzle. B: pre-repacked Wfrag (global, L2).
// ---------------------------------------------------------------------------
__global__ __launch_bounds__(256, 4) void k_fuse0_conv(
    const float* __restrict__ basep, const ushort* __restrict__ Wfrag,
    const float* __restrict__ b0, ushort* __restrict__ f0c, double* __restrict__ part)
{
    __shared__ ushort lds_x[108 * 64];   // 13824 B, byte layout: px*128 + (c*2 ^ ((px&7)<<4))
    __shared__ double red[8];
    const int tid = threadIdx.x;
    const int lane = tid & 63, w = tid >> 6;
    const int bz = blockIdx.z;
    const int y0 = blockIdx.y * 4;
    const int x0 = blockIdx.x * 16;

    for (int i = tid; i < 6912; i += 256) {
        int c = i / 108, p = i - c * 108;
        int hy = p / 18, hx = p - hy * 18;
        int gy = y0 + hy - 1, gx = x0 + hx - 1;
        float v = 0.f;
        if ((uint)gy < 300u && (uint)gx < 300u)
            v = basep[(size_t)(bz * 64 + c) * HWp + gy * 300 + gx];
        int byteoff = p * 128 + ((c * 2) ^ ((p & 7) << 4));
        *(ushort*)((char*)lds_x + byteoff) = f2bf(v);
    }
    __syncthreads();

    f32x4 acc[4];
#pragma unroll
    for (int ot = 0; ot < 4; ++ot) acc[ot] = f32x4{0.f, 0.f, 0.f, 0.f};
    const int mg = lane >> 4;     // k-slice group (and D-row group)
    const int mr = lane & 15;     // A: pixel (M); B/D: oc (N)
#pragma unroll
    for (int tap = 0; tap < 9; ++tap) {
        const int dy = tap / 3, dx = tap % 3;
        const int p = (w + dy) * 18 + (mr + dx);
#pragma unroll
        for (int ks = 0; ks < 2; ++ks) {
            int slot = ks * 4 + mg;
            int byteoff = p * 128 + ((slot * 16) ^ ((p & 7) << 4));
            bf16x8 a = *(bf16x8*)((char*)lds_x + byteoff);
            const ushort* wp = Wfrag + (((size_t)(tap * 2 + ks) * 4) * 64 + lane) * 8;
#pragma unroll
            for (int ot = 0; ot < 4; ++ot) {
                bf16x8 bv = *(const bf16x8*)(wp + ot * 512);
                acc[ot] = __builtin_amdgcn_mfma_f32_16x16x32_bf16(a, bv, acc[ot], 0, 0, 0);
            }
        }
    }
    // epilogue: D[m][n]: pixel = mg*4+i, oc = ot*16+mr
    const int yo = y0 + w;
    float s = 0.f, ss = 0.f;
#pragma unroll
    for (int ot = 0; ot < 4; ++ot) {
        int oc = ot * 16 + mr;
        float bia = b0[oc];
#pragma unroll
        for (int i2 = 0; i2 < 4; ++i2) {
            int xo = x0 + mg * 4 + i2;
            if (xo < 300) {
                float t = acc[ot][i2] + bia;
                f0c[((size_t)(bz * 300 + yo) * 300 + xo) * 64 + oc] = f2bf(t);
                s += t; ss += t * t;
            }
        }
    }
    double ds = s, dss = ss;
    for (int off = 32; off; off >>= 1) { ds += __shfl_down(ds, off); dss += __shfl_down(dss, off); }
    if (lane == 0) { red[w * 2] = ds; red[w * 2 + 1] = dss; }
    __syncthreads();
    if (tid == 0) {
        double S = red[0] + red[2] + red[4] + red[6];
        double SS = red[1] + red[3] + red[5] + red[7];
        int blin = (bz * 75 + blockIdx.y) * 19 + blockIdx.x;
        part[2 * blin] = S; part[2 * blin + 1] = SS;
    }
}

// reduce (sum,sumsq) partials -> (mu, rsqrt(var+eps))
__global__ __launch_bounds__(64) void k_redstats(const double* __restrict__ part, int cnt,
                                                 double invN, float* __restrict__ stats)
{
    int b = blockIdx.x, t = threadIdx.x;
    double s = 0, ss = 0;
    for (int i = t; i < cnt; i += 64) { s += part[2 * (b * cnt + i)]; ss += part[2 * (b * cnt + i) + 1]; }
    for (int off = 32; off; off >>= 1) { s += __shfl_down(s, off); ss += __shfl_down(ss, off); }
    if (t == 0) {
        double mu = s * invN;
        double var = ss * invN - mu * mu;
        stats[2 * b] = (float)mu;
        stats[2 * b + 1] = (float)(1.0 / sqrt(var + 1e-5));
    }
}

__global__ __launch_bounds__(64) void k_redmean(const double* __restrict__ part, int cnt,
                                                double invN, float* __restrict__ out)
{
    int b = blockIdx.x, t = threadIdx.x;
    double s = 0;
    for (int i = t; i < cnt; i += 64) s += part[b * cnt + i];
    for (int off = 32; off; off >>= 1) s += __shfl_down(s, off);
    if (t == 0) out[b] = (float)(s * invN);
}

// GN+ReLU in place (preb -> base) + bcg 1x1 conv + sigmoid + per-block bcg sums
__global__ __launch_bounds__(256) void k_finalize(
    float* __restrict__ basep, float* __restrict__ bcg_out,
    const float* __restrict__ fg, const float* __restrict__ fbe,
    const float* __restrict__ wb, const float* __restrict__ bb,
    const float* __restrict__ fstats, double* __restrict__ bcgpart)
{
    const int b = blockIdx.y;
    const int idx = blockIdx.x * 256 + threadIdx.x;
    float lsum = 0.f;
    if (idx < 22500) {
        const int p4 = idx * 4;
        const float mu = fstats[b * 2], rs = fstats[b * 2 + 1];
        float4 acc = make_float4(0.f, 0.f, 0.f, 0.f);
        for (int c = 0; c < 64; ++c) {
            float* ptr = basep + ((size_t)(b * 64 + c)) * HWp + p4;
            float4 v = *(float4*)ptr;
            const float g = fg[c], be = fbe[c];
            float4 t;
            t.x = fmaxf((v.x - mu) * rs * g + be, 0.f);
            t.y = fmaxf((v.y - mu) * rs * g + be, 0.f);
            t.z = fmaxf((v.z - mu) * rs * g + be, 0.f);
            t.w = fmaxf((v.w - mu) * rs * g + be, 0.f);
            *(float4*)ptr = t;
            const float wc = wb[c];
            acc.x = fmaf(wc, t.x, acc.x);
            acc.y = fmaf(wc, t.y, acc.y);
            acc.z = fmaf(wc, t.z, acc.z);
            acc.w = fmaf(wc, t.w, acc.w);
        }
        const float bz = bb[0];
        float4 sg;
        sg.x = 1.f / (1.f + expf(-(acc.x + bz)));
        sg.y = 1.f / (1.f + expf(-(acc.y + bz)));
        sg.z = 1.f / (1.f + expf(-(acc.z + bz)));
        sg.w = 1.f / (1.f + expf(-(acc.w + bz)));
        *(float4*)(bcg_out + (size_t)b * HWp + p4) = sg;
        lsum = sg.x + sg.y + sg.z + sg.w;
    }
    double d = lsum;
    for (int off = 32; off; off >>= 1) d += __shfl_down(d, off);
    __shared__ double rr[4];
    int wid = threadIdx.x >> 6, lane = threadIdx.x & 63;
    if (lane == 0) rr[wid] = d;
    __syncthreads();
    if (threadIdx.x == 0) bcgpart[b * 88 + blockIdx.x] = rr[0] + rr[1] + rr[2] + rr[3];
}

// fdm_m = fdm * (bcg > mean); pooled = 10x10 window max of fdm_m
__global__ __launch_bounds__(128) void k_maskpool(
    const float* __restrict__ fdm, const float* __restrict__ bcg,
    const float* __restrict__ bcgmean, float* __restrict__ fdm_m, float* __restrict__ pooled)
{
    const int cell = blockIdx.x;
    const int b = blockIdx.y;
    const int t = threadIdx.x;
    const int cy = cell / 30, cx = cell - cy * 30;
    float m = -INFINITY;
    if (t < 100) {
        int yy = cy * 10 + t / 10, xx = cx * 10 + t % 10;
        size_t p = (size_t)b * HWp + yy * 300 + xx;
        float v = (bcg[p] > bcgmean[b]) ? fdm[p] : 0.f;
        fdm_m[p] = v;
        m = v;
    }
    for (int off = 32; off; off >>= 1) m = fmaxf(m, __shfl_down(m, off));
    __shared__ float rr[2];
    if ((t & 63) == 0) rr[t >> 6] = m;
    __syncthreads();
    if (t == 0) pooled[b * 900 + cell] = fmaxf(rr[0], rr[1]);
}

// vertical antialiased triangle downsample of relu(GN(f0conv)) : 300 -> 30 rows
__global__ __launch_bounds__(256) void k_vert(
    const ushort* __restrict__ f0c, const float* __restrict__ g0, const float* __restrict__ be0,
    const float* __restrict__ f0stats, float* __restrict__ vtmp)
{
    const int idx = blockIdx.x * 256 + threadIdx.x;
    if (idx >= 4 * 30 * 300 * 64) return;
    const int c = idx & 63;
    int rest = idx >> 6;
    const int x = rest % 300; rest /= 300;
    const int j = rest % 30;
    const int b = rest / 30;
    const float mu = f0stats[2 * b], rs = f0stats[2 * b + 1];
    const float gg = g0[c], bb = be0[c];
    const int ylo = max(0, 10 * j - 5), yhi = min(299, 10 * j + 14);
    const float centre = (float)(10 * j) + 4.5f;
    float acc = 0.f, wsum = 0.f;
    for (int yy = ylo; yy <= yhi; ++yy) {
        float w = 1.0f - fabsf((float)yy - centre) * 0.1f;
        float v = bf2f(f0c[(((size_t)b * 300 + yy) * 300 + x) * 64 + c]);
        float t = fmaxf((v - mu) * rs * gg + bb, 0.f);
        acc = fmaf(w, t, acc);
        wsum += w;
    }
    vtmp[idx] = acc / wsum;
}

// horizontal pass: 300 -> 30 cols; emit B = nl30, A = pooled*nl30, layout [b][sp][c]
__global__ __launch_bounds__(256) void k_horiz(
    const float* __restrict__ vtmp, const float* __restrict__ pooled,
    float* __restrict__ A, float* __restrict__ Bm)
{
    const int idx = blockIdx.x * 256 + threadIdx.x;
    if (idx >= 4 * 30 * 30 * 64) return;
    const int c = idx & 63;
    int rest = idx >> 6;
    const int i = rest % 30; rest /= 30;
    const int j = rest % 30;
    const int b = rest / 30;
    const int xlo = max(0, 10 * i - 5), xhi = min(299, 10 * i + 14);
    const float centre = (float)(10 * i) + 4.5f;
    float acc = 0.f, wsum = 0.f;
    for (int xx = xlo; xx <= xhi; ++xx) {
        float w = 1.0f - fabsf((float)xx - centre) * 0.1f;
        acc = fmaf(w, vtmp[(((size_t)b * 30 + j) * 300 + xx) * 64 + c], acc);
        wsum += w;
    }
    float nl30 = acc / wsum;
    Bm[idx] = nl30;
    A[idx] = pooled[b * 900 + j * 30 + i] * nl30;
}

// nl[b,i] = max_j sum_c A[b,i,c]*B[b,j,c]  (atomicMax on encoded key)
__global__ __launch_bounds__(256) void k_nl(
    const float* __restrict__ A, const float* __restrict__ Bm, uint* __restrict__ nlkey)
{
    __shared__ float lb[75 * 64];
    const int b = blockIdx.z;
    const int j0 = blockIdx.x * 75;
    const int i1 = blockIdx.y * 512 + threadIdx.x;
    const int i2 = i1 + 256;
    for (int s = threadIdx.x; s < 75 * 64; s += 256)
        lb[s] = Bm[(size_t)(b * 900 + j0) * 64 + s];
    __syncthreads();
    const bool v1 = i1 < 900, v2 = i2 < 900;
    float a1[64], a2[64];
    const float* A1 = A + (size_t)(b * 900 + i1) * 64;
    const float* A2 = A + (size_t)(b * 900 + i2) * 64;
#pragma unroll
    for (int c = 0; c < 64; ++c) { a1[c] = v1 ? A1[c] : 0.f; a2[c] = v2 ? A2[c] : 0.f; }
    float m1 = -INFINITY, m2 = -INFINITY;
    for (int jj = 0; jj < 75; ++jj) {
        const float* bp = lb + jj * 64;
        float d1 = 0.f, d2 = 0.f;
#pragma unroll
        for (int c = 0; c < 64; ++c) { float bv = bp[c]; d1 = fmaf(a1[c], bv, d1); d2 = fmaf(a2[c], bv, d2); }
        m1 = fmaxf(m1, d1); m2 = fmaxf(m2, d2);
    }
    if (v1) atomicMax(&nlkey[b * 900 + i1], enc(m1));
    if (v2) atomicMax(&nlkey[b * 900 + i2], enc(m2));
}

// base2 = upsample(nl,30->300) * base; sup = 1x1 conv of base2
__global__ __launch_bounds__(256) void k_base2_sup(
    const float* __restrict__ basep, const uint* __restrict__ nlkey,
    const float* __restrict__ wsup, const float* __restrict__ bsup,
    float* __restrict__ out_b2, float* __restrict__ out_sup)
{
    const int b = blockIdx.y;
    const int idx = blockIdx.x * 256 + threadIdx.x;
    if (idx >= 22500) return;
    const int p4 = idx * 4;
    const int yy = p4 / 300, xx = p4 - yy * 300;
    const uint* nk = nlkey + b * 900;
    float cyf = ((float)yy + 0.5f) * 0.1f - 0.5f;
    int iy = (int)floorf(cyf);
    float ay = cyf - (float)iy;
    int jy0 = min(max(iy, 0), 29), jy1 = min(iy + 1, 29);
    float e[4];
#pragma unroll
    for (int k = 0; k < 4; ++k) {
        float cxf = ((float)(xx + k) + 0.5f) * 0.1f - 0.5f;
        int ix = (int)floorf(cxf);
        float ax = cxf - (float)ix;
        int jx0 = min(max(ix, 0), 29), jx1 = min(ix + 1, 29);
        float n00 = dec(nk[jy0 * 30 + jx0]), n01 = dec(nk[jy0 * 30 + jx1]);
        float n10 = dec(nk[jy1 * 30 + jx0]), n11 = dec(nk[jy1 * 30 + jx1]);
        e[k] = (1.f - ay) * ((1.f - ax) * n00 + ax * n01) + ay * ((1.f - ax) * n10 + ax * n11);
    }
    float4 sacc = make_float4(0.f, 0.f, 0.f, 0.f);
    for (int c = 0; c < 64; ++c) {
        size_t off = ((size_t)(b * 64 + c)) * HWp + p4;
        float4 v = *(const float4*)(basep + off);
        float4 t;
        t.x = v.x * e[0]; t.y = v.y * e[1]; t.z = v.z * e[2]; t.w = v.w * e[3];
        *(float4*)(out_b2 + off) = t;
        const float wc = wsup[c];
        sacc.x = fmaf(wc, t.x, sacc.x);
        sacc.y = fmaf(wc, t.y, sacc.y);
        sacc.z = fmaf(wc, t.z, sacc.z);
        sacc.w = fmaf(wc, t.w, sacc.w);
    }
    const float bz = bsup[0];
    float4 so;
    so.x = sacc.x + bz; so.y = sacc.y + bz; so.z = sacc.z + bz; so.w = sacc.w + bz;
    *(float4*)(out_sup + (size_t)b * HWp + p4) = so;
}

// ---------------------------------------------------------------------------
extern "C" void kernel_launch(void* const* d_in, const int* in_sizes, int n_in,
                              void* d_out, int out_size, void* d_ws, size_t ws_size,
                              hipStream_t stream)
{
    (void)in_sizes; (void)n_in; (void)out_size; (void)ws_size;
    const float* fdm     = (const float*)d_in[0];
    const float* x2      = (const float*)d_in[3];
    const float* x3      = (const float*)d_in[4];
    const float* x4      = (const float*)d_in[5];
    const float* fuse_W  = (const float*)d_in[6];
    const float* fuse_b  = (const float*)d_in[7];
    const float* fuse_g  = (const float*)d_in[8];
    const float* fuse_be = (const float*)d_in[9];
    const float* bcg_W   = (const float*)d_in[10];
    const float* bcg_b   = (const float*)d_in[11];
    const float* f0_W    = (const float*)d_in[12];
    const float* f0_b    = (const float*)d_in[13];
    const float* f0_g    = (const float*)d_in[14];
    const float* f0_be   = (const float*)d_in[15];
    const float* sup_W   = (const float*)d_in[16];
    const float* sup_b   = (const float*)d_in[17];

    // workspace layout (bytes)
    char* ws = (char*)d_ws;
    float*  basep    = (float*)ws;                                // 92,160,000 B
    ushort* f0c      = (ushort*)(ws + 92160000);                  // 46,080,000 B
    double* fusepart = (double*)(ws + 138240000);                 // 1520 dbl
    double* f0part   = (double*)(ws + 138252160);                 // 11400 dbl (4 x 1425 x 2)
    double* bcgpart  = (double*)(ws + 138343360);                 // 352 dbl
    float*  fext     = (float*)(ws + 138346176);
    float*  fstats   = fext;            // 8
    float*  f0stats  = fext + 8;        // 8
    float*  bcgmean  = fext + 16;       // 4
    float*  pooled   = fext + 32;       // 3600
    float*  Abuf     = fext + 4000;     // 230400
    float*  Bbuf     = fext + 234400;   // 230400
    uint*   nlkey    = (uint*)(fext + 464800); // 3600
    float*  vtmp     = (float*)(ws + 140219776);                  // 9,216,000 B
    // weight repacks overlap vtmp's region: used only BEFORE k_vert writes vtmp
    float*  Wre      = (float*)(ws + 140219776);                  // 442,368 B
    ushort* Wfrag    = (ushort*)(ws + 140662144);                 // 73,728 B

    float* o_fdm  = (float*)d_out;
    float* o_bcg  = o_fdm + 360000;
    float* o_b2   = o_fdm + 720000;
    float* o_sup  = o_fdm + 23760000;

    k_repack_fuse<<<432, 256, 0, stream>>>(fuse_W, Wre);
    k_repack_f0<<<144, 256, 0, stream>>>(f0_W, Wfrag);
    k_fuse_conv<<<dim3(5, 38, 4), 512, 0, stream>>>(x2, x3, x4, Wre, fuse_b, basep, fusepart);
    k_redstats<<<4, 64, 0, stream>>>(fusepart, 190, 1.0 / 5760000.0, fstats);
    k_finalize<<<dim3(88, 4), 256, 0, stream>>>(basep, o_bcg, fuse_g, fuse_be, bcg_W, bcg_b, fstats, bcgpart);
    k_redmean<<<4, 64, 0, stream>>>(bcgpart, 88, 1.0 / 90000.0, bcgmean);
    k_maskpool<<<dim3(900, 4), 128, 0, stream>>>(fdm, o_bcg, bcgmean, o_fdm, pooled);
    k_fuse0_conv<<<dim3(19, 75, 4), 256, 0, stream>>>(basep, Wfrag, f0_b, f0c, f0part);
    k_redstats<<<4, 64, 0, stream>>>(f0part, 1425, 1.0 / 5760000.0, f0stats);
    k_vert<<<9000, 256, 0, stream>>>(f0c, f0_g, f0_be, f0stats, vtmp);
    k_horiz<<<900, 256, 0, stream>>>(vtmp, pooled, Abuf, Bbuf);
    hipMemsetAsync(nlkey, 0, 3600 * sizeof(uint), stream);
    k_nl<<<dim3(12, 2, 4), 256, 0, stream>>>(Abuf, Bbuf, nlkey);
    k_base2_sup<<<dim3(88, 4), 256, 0, stream>>>(basep, nlkey, sup_W, sup_b, o_b2, o_sup);
}

// Round 6
// 902.556 us; speedup vs baseline: 2.1548x; 1.8734x over previous
//
#include <hip/hip_runtime.h>
#include <math.h>

typedef unsigned int uint;
typedef unsigned short ushort;
typedef __attribute__((ext_vector_type(8))) short bf16x8;
typedef __attribute__((ext_vector_type(8))) _Float16 f16x8;
typedef __attribute__((ext_vector_type(4))) float f32x4;

#define HWp 90000

__device__ __forceinline__ float bf2f(ushort u) { return __uint_as_float(((uint)u) << 16); }
__device__ __forceinline__ ushort f2bf(float f) {
    uint u = __float_as_uint(f);
    uint r = (u + 0x7FFFu + ((u >> 16) & 1u)) >> 16;
    return (ushort)r;
}
__device__ __forceinline__ ushort f2h(float f) { _Float16 h = (_Float16)f; ushort u; __builtin_memcpy(&u, &h, 2); return u; }
__device__ __forceinline__ float h2f(ushort u) { _Float16 h; __builtin_memcpy(&h, &u, 2); return (float)h; }
__device__ __forceinline__ uint enc(float f) {
    uint u = __float_as_uint(f);
    return (u & 0x80000000u) ? ~u : (u | 0x80000000u);
}
__device__ __forceinline__ float dec(uint k) {
    uint u = (k & 0x80000000u) ? (k ^ 0x80000000u) : ~k;
    return __uint_as_float(u);
}

// ---------------------------------------------------------------------------
// Wsplit[wsel][ck][tap][n][lane][j] f16 <- fuse_W [oc][c][tap] * 256, hi/lo split
// oc = n*16 + (lane&15), c = ck*32 + (lane>>4)*8 + j
__global__ __launch_bounds__(256) void k_repack_fsplit(const float* __restrict__ Wf, ushort* __restrict__ Ws) {
    int i = blockIdx.x * 256 + threadIdx.x;       // 2*6*9*4*64*8 = 221184
    if (i >= 221184) return;
    int j = i & 7; int l = (i >> 3) & 63; int n = (i >> 9) & 3;
    int r = i >> 11; int tap = r % 9; int ck = (r / 9) % 6; int wsel = r / 54;
    int oc = n * 16 + (l & 15);
    int c  = ck * 32 + ((l >> 4) << 3) + j;
    float w = Wf[(size_t)oc * 1728 + c * 9 + tap] * 256.0f;
    ushort h = f2h(w);
    Ws[i] = wsel ? f2h(w - h2f(h)) : h;
}
// Wfrag[tap][kstep][octile][lane][j] bf16 <- fuse0_W [oc][c][tap]
__global__ __launch_bounds__(256) void k_repack_f0(const float* __restrict__ W0, ushort* __restrict__ Wfrag) {
    int i = blockIdx.x * 256 + threadIdx.x;       // 9*2*4*64*8 = 36864
    if (i >= 36864) return;
    int j = i & 7; int l = (i >> 3) & 63; int octile = (i >> 9) & 3;
    int kstep = (i >> 11) & 1; int tap = i >> 12;
    int oc = octile * 16 + (l & 15);
    int c  = kstep * 32 + (l >> 4) * 8 + j;
    Wfrag[i] = f2bf(W0[(size_t)oc * 576 + c * 9 + tap]);
}

// ---------------------------------------------------------------------------
// k_fuse_mfma: conv3x3(cat(resize(x2),resize(x3),resize(x4)), 192->64) + bias
// via f16x2 split-precision MFMA: a*w = ah*wh + al*wh + ah*wl, inputs scaled x256.
// 256 thr = 4 waves; tile 4 rows x 16 cols; wave w owns row w, all 64 oc.
// LDS A: [108 px][144 B]: hi f16 ch*2 at +0..63, lo at +64..127, pad to 144.
// ---------------------------------------------------------------------------
__global__ __launch_bounds__(256, 4) void k_fuse_mfma(
    const float* __restrict__ x2, const float* __restrict__ x3, const float* __restrict__ x4,
    const ushort* __restrict__ Ws, const float* __restrict__ bfv,
    float* __restrict__ preb, double* __restrict__ part)
{
    __shared__ char lds_a[108 * 144];
    __shared__ int   t_y0[18], t_y1[18];
    __shared__ float t_wy[18];
    __shared__ int   t_x0[54], t_x1[54];
    __shared__ float t_wx[54];
    __shared__ double red[8];
    const int tid = threadIdx.x;
    const int lane = tid & 63, w = tid >> 6;
    const int bz = blockIdx.z;
    const int y0 = blockIdx.y * 4;
    const int x0 = blockIdx.x * 16;
    const int mg = lane >> 4, mr = lane & 15;

    // bilinear coord tables: 3 levels x (6 rows + 18 cols)
    for (int i = tid; i < 72; i += 256) {
        int lev = i / 24, k = i - lev * 24;
        int n = (lev == 0) ? 75 : (lev == 1 ? 38 : 19);
        float scale = (float)n * (1.0f / 300.0f);
        if (k < 6) {
            int gy = y0 + k - 1;
            float fy = ((float)gy + 0.5f) * scale - 0.5f;
            float fl = floorf(fy); int iy = (int)fl; float ay = fy - fl;
            t_y0[lev * 6 + k] = min(max(iy, 0), n - 1) * n;
            t_y1[lev * 6 + k] = min(iy + 1, n - 1) * n;
            t_wy[lev * 6 + k] = ay;
        } else {
            int j = k - 6;
            int gx = x0 + j - 1;
            float fx = ((float)gx + 0.5f) * scale - 0.5f;
            float fl = floorf(fx); int ix = (int)fl; float ax = fx - fl;
            t_x0[lev * 18 + j] = min(max(ix, 0), n - 1);
            t_x1[lev * 18 + j] = min(ix + 1, n - 1);
            t_wx[lev * 18 + j] = ax;
        }
    }
    __syncthreads();

    f32x4 acc[4];
#pragma unroll
    for (int ot = 0; ot < 4; ++ot) acc[ot] = f32x4{0.f, 0.f, 0.f, 0.f};

    for (int ck = 0; ck < 6; ++ck) {
        const int lev = ck >> 1;
        const float* src = (lev == 0) ? x2 : (lev == 1 ? x3 : x4);
        const int n = (lev == 0) ? 75 : (lev == 1 ? 38 : 19);
        const float* plane0 = src + (size_t)(bz * 64 + (ck & 1) * 32) * n * n;
        // stage 108 px x 32 ch, resized+scaled+split
        for (int e = tid; e < 3456; e += 256) {
            int ch = e / 108;
            int px = e - ch * 108;
            int hy = px / 18, hx = px - hy * 18;
            int gy = y0 + hy - 1, gx = x0 + hx - 1;
            float a = 0.f;
            if ((uint)gy < 300u && (uint)gx < 300u) {
                const float* sp = plane0 + (size_t)ch * n * n;
                int r0 = t_y0[lev * 6 + hy], r1 = t_y1[lev * 6 + hy]; float fy = t_wy[lev * 6 + hy];
                int c0 = t_x0[lev * 18 + hx], c1 = t_x1[lev * 18 + hx]; float fx = t_wx[lev * 18 + hx];
                float v00 = sp[r0 + c0], v01 = sp[r0 + c1];
                float v10 = sp[r1 + c0], v11 = sp[r1 + c1];
                a = ((1.f - fy) * ((1.f - fx) * v00 + fx * v01)
                   + fy * ((1.f - fx) * v10 + fx * v11)) * 256.0f;
            }
            ushort hi = f2h(a);
            ushort lo = f2h(a - h2f(hi));
            char* p = lds_a + px * 144 + ch * 2;
            *(ushort*)p = hi;
            *(ushort*)(p + 64) = lo;
        }
        __syncthreads();
#pragma unroll
        for (int tap = 0; tap < 9; ++tap) {
            const int p = (w + tap / 3) * 18 + (mr + tap % 3);
            const char* ap = lds_a + p * 144 + mg * 16;
            f16x8 ah = *(const f16x8*)ap;
            f16x8 al = *(const f16x8*)(ap + 64);
            const ushort* wh = Ws + ((size_t)(ck * 9 + tap)) * 2048 + lane * 8;
            const ushort* wl = wh + 54 * 2048;
#pragma unroll
            for (int ot = 0; ot < 4; ++ot) {
                f16x8 bh = *(const f16x8*)(wh + ot * 512);
                acc[ot] = __builtin_amdgcn_mfma_f32_16x16x32_f16(ah, bh, acc[ot], 0, 0, 0);
                acc[ot] = __builtin_amdgcn_mfma_f32_16x16x32_f16(al, bh, acc[ot], 0, 0, 0);
                f16x8 bl = *(const f16x8*)(wl + ot * 512);
                acc[ot] = __builtin_amdgcn_mfma_f32_16x16x32_f16(ah, bl, acc[ot], 0, 0, 0);
            }
        }
        __syncthreads();
    }
    // epilogue: rescale 2^-16, bias, store f32, stats. D: oc=ot*16+mr, xo=x0+mg*4+i2
    const int yo = y0 + w;
    float s = 0.f, ss = 0.f;
#pragma unroll
    for (int ot = 0; ot < 4; ++ot) {
        int oc = ot * 16 + mr;
        float bia = bfv[oc];
#pragma unroll
        for (int i2 = 0; i2 < 4; ++i2) {
            int xo = x0 + mg * 4 + i2;
            if (xo < 300) {
                float t = acc[ot][i2] * (1.0f / 65536.0f) + bia;
                preb[(size_t)(bz * 64 + oc) * HWp + yo * 300 + xo] = t;
                s += t; ss += t * t;
            }
        }
    }
    double ds = s, dss = ss;
    for (int off = 32; off; off >>= 1) { ds += __shfl_down(ds, off); dss += __shfl_down(dss, off); }
    if (lane == 0) { red[w * 2] = ds; red[w * 2 + 1] = dss; }
    __syncthreads();
    if (tid == 0) {
        double S = red[0] + red[2] + red[4] + red[6];
        double SS = red[1] + red[3] + red[5] + red[7];
        int blin = (bz * 75 + blockIdx.y) * 19 + blockIdx.x;
        part[2 * blin] = S; part[2 * blin + 1] = SS;
    }
}

// ---------------------------------------------------------------------------
// k_fuse0_conv (MFMA): conv3x3(base, 64->64) + bias -> bf16 [b][y][x][c] + stats
// ---------------------------------------------------------------------------
__global__ __launch_bounds__(256, 4) void k_fuse0_conv(
    const float* __restrict__ basep, const ushort* __restrict__ Wfrag,
    const float* __restrict__ b0, ushort* __restrict__ f0c, double* __restrict__ part)
{
    __shared__ ushort lds_x[108 * 64];   // byte layout: px*128 + (c*2 ^ ((px&7)<<4))
    __shared__ double red[8];
    const int tid = threadIdx.x;
    const int lane = tid & 63, w = tid >> 6;
    const int bz = blockIdx.z;
    const int y0 = blockIdx.y * 4;
    const int x0 = blockIdx.x * 16;

    for (int i = tid; i < 6912; i += 256) {
        int c = i / 108, p = i - c * 108;
        int hy = p / 18, hx = p - hy * 18;
        int gy = y0 + hy - 1, gx = x0 + hx - 1;
        float v = 0.f;
        if ((uint)gy < 300u && (uint)gx < 300u)
            v = basep[(size_t)(bz * 64 + c) * HWp + gy * 300 + gx];
        int byteoff = p * 128 + ((c * 2) ^ ((p & 7) << 4));
        *(ushort*)((char*)lds_x + byteoff) = f2bf(v);
    }
    __syncthreads();

    f32x4 acc[4];
#pragma unroll
    for (int ot = 0; ot < 4; ++ot) acc[ot] = f32x4{0.f, 0.f, 0.f, 0.f};
    const int mg = lane >> 4;
    const int mr = lane & 15;
#pragma unroll
    for (int tap = 0; tap < 9; ++tap) {
        const int dy = tap / 3, dx = tap % 3;
        const int p = (w + dy) * 18 + (mr + dx);
#pragma unroll
        for (int ks = 0; ks < 2; ++ks) {
            int slot = ks * 4 + mg;
            int byteoff = p * 128 + ((slot * 16) ^ ((p & 7) << 4));
            bf16x8 a = *(bf16x8*)((char*)lds_x + byteoff);
            const ushort* wp = Wfrag + (((size_t)(tap * 2 + ks) * 4) * 64 + lane) * 8;
#pragma unroll
            for (int ot = 0; ot < 4; ++ot) {
                bf16x8 bv = *(const bf16x8*)(wp + ot * 512);
                acc[ot] = __builtin_amdgcn_mfma_f32_16x16x32_bf16(a, bv, acc[ot], 0, 0, 0);
            }
        }
    }
    const int yo = y0 + w;
    float s = 0.f, ss = 0.f;
#pragma unroll
    for (int ot = 0; ot < 4; ++ot) {
        int oc = ot * 16 + mr;
        float bia = b0[oc];
#pragma unroll
        for (int i2 = 0; i2 < 4; ++i2) {
            int xo = x0 + mg * 4 + i2;
            if (xo < 300) {
                float t = acc[ot][i2] + bia;
                f0c[((size_t)(bz * 300 + yo) * 300 + xo) * 64 + oc] = f2bf(t);
                s += t; ss += t * t;
            }
        }
    }
    double ds = s, dss = ss;
    for (int off = 32; off; off >>= 1) { ds += __shfl_down(ds, off); dss += __shfl_down(dss, off); }
    if (lane == 0) { red[w * 2] = ds; red[w * 2 + 1] = dss; }
    __syncthreads();
    if (tid == 0) {
        double S = red[0] + red[2] + red[4] + red[6];
        double SS = red[1] + red[3] + red[5] + red[7];
        int blin = (bz * 75 + blockIdx.y) * 19 + blockIdx.x;
        part[2 * blin] = S; part[2 * blin + 1] = SS;
    }
}

// reduce (sum,sumsq) partials -> (mu, rsqrt(var+eps))
__global__ __launch_bounds__(64) void k_redstats(const double* __restrict__ part, int cnt,
                                                 double invN, float* __restrict__ stats)
{
    int b = blockIdx.x, t = threadIdx.x;
    double s = 0, ss = 0;
    for (int i = t; i < cnt; i += 64) { s += part[2 * (b * cnt + i)]; ss += part[2 * (b * cnt + i) + 1]; }
    for (int off = 32; off; off >>= 1) { s += __shfl_down(s, off); ss += __shfl_down(ss, off); }
    if (t == 0) {
        double mu = s * invN;
        double var = ss * invN - mu * mu;
        stats[2 * b] = (float)mu;
        stats[2 * b + 1] = (float)(1.0 / sqrt(var + 1e-5));
    }
}

__global__ __launch_bounds__(64) void k_redmean(const double* __restrict__ part, int cnt,
                                                double invN, float* __restrict__ out)
{
    int b = blockIdx.x, t = threadIdx.x;
    double s = 0;
    for (int i = t; i < cnt; i += 64) s += part[b * cnt + i];
    for (int off = 32; off; off >>= 1) s += __shfl_down(s, off);
    if (t == 0) out[b] = (float)(s * invN);
}

// GN+ReLU in place (preb -> base) + bcg 1x1 conv + sigmoid + per-block bcg sums
__global__ __launch_bounds__(256) void k_finalize(
    float* __restrict__ basep, float* __restrict__ bcg_out,
    const float* __restrict__ fg, const float* __restrict__ fbe,
    const float* __restrict__ wb, const float* __restrict__ bb,
    const float* __restrict__ fstats, double* __restrict__ bcgpart)
{
    const int b = blockIdx.y;
    const int idx = blockIdx.x * 256 + threadIdx.x;
    float lsum = 0.f;
    if (idx < 22500) {
        const int p4 = idx * 4;
        const float mu = fstats[b * 2], rs = fstats[b * 2 + 1];
        float4 acc = make_float4(0.f, 0.f, 0.f, 0.f);
        for (int c = 0; c < 64; ++c) {
            float* ptr = basep + ((size_t)(b * 64 + c)) * HWp + p4;
            float4 v = *(float4*)ptr;
            const float g = fg[c], be = fbe[c];
            float4 t;
            t.x = fmaxf((v.x - mu) * rs * g + be, 0.f);
            t.y = fmaxf((v.y - mu) * rs * g + be, 0.f);
            t.z = fmaxf((v.z - mu) * rs * g + be, 0.f);
            t.w = fmaxf((v.w - mu) * rs * g + be, 0.f);
            *(float4*)ptr = t;
            const float wc = wb[c];
            acc.x = fmaf(wc, t.x, acc.x);
            acc.y = fmaf(wc, t.y, acc.y);
            acc.z = fmaf(wc, t.z, acc.z);
            acc.w = fmaf(wc, t.w, acc.w);
        }
        const float bz = bb[0];
        float4 sg;
        sg.x = 1.f / (1.f + expf(-(acc.x + bz)));
        sg.y = 1.f / (1.f + expf(-(acc.y + bz)));
        sg.z = 1.f / (1.f + expf(-(acc.z + bz)));
        sg.w = 1.f / (1.f + expf(-(acc.w + bz)));
        *(float4*)(bcg_out + (size_t)b * HWp + p4) = sg;
        lsum = sg.x + sg.y + sg.z + sg.w;
    }
    double d = lsum;
    for (int off = 32; off; off >>= 1) d += __shfl_down(d, off);
    __shared__ double rr[4];
    int wid = threadIdx.x >> 6, lane = threadIdx.x & 63;
    if (lane == 0) rr[wid] = d;
    __syncthreads();
    if (threadIdx.x == 0) bcgpart[b * 88 + blockIdx.x] = rr[0] + rr[1] + rr[2] + rr[3];
}

// fdm_m = fdm * (bcg > mean); pooled = 10x10 window max of fdm_m
__global__ __launch_bounds__(128) void k_maskpool(
    const float* __restrict__ fdm, const float* __restrict__ bcg,
    const float* __restrict__ bcgmean, float* __restrict__ fdm_m, float* __restrict__ pooled)
{
    const int cell = blockIdx.x;
    const int b = blockIdx.y;
    const int t = threadIdx.x;
    const int cy = cell / 30, cx = cell - cy * 30;
    float m = -INFINITY;
    if (t < 100) {
        int yy = cy * 10 + t / 10, xx = cx * 10 + t % 10;
        size_t p = (size_t)b * HWp + yy * 300 + xx;
        float v = (bcg[p] > bcgmean[b]) ? fdm[p] : 0.f;
        fdm_m[p] = v;
        m = v;
    }
    for (int off = 32; off; off >>= 1) m = fmaxf(m, __shfl_down(m, off));
    __shared__ float rr[2];
    if ((t & 63) == 0) rr[t >> 6] = m;
    __syncthreads();
    if (t == 0) pooled[b * 900 + cell] = fmaxf(rr[0], rr[1]);
}

// vertical antialiased triangle downsample of relu(GN(f0conv)) : 300 -> 30 rows
__global__ __launch_bounds__(256) void k_vert(
    const ushort* __restrict__ f0c, const float* __restrict__ g0, const float* __restrict__ be0,
    const float* __restrict__ f0stats, float* __restrict__ vtmp)
{
    const int idx = blockIdx.x * 256 + threadIdx.x;
    if (idx >= 4 * 30 * 300 * 64) return;
    const int c = idx & 63;
    int rest = idx >> 6;
    const int x = rest % 300; rest /= 300;
    const int j = rest % 30;
    const int b = rest / 30;
    const float mu = f0stats[2 * b], rs = f0stats[2 * b + 1];
    const float gg = g0[c], bb = be0[c];
    const int ylo = max(0, 10 * j - 5), yhi = min(299, 10 * j + 14);
    const float centre = (float)(10 * j) + 4.5f;
    float acc = 0.f, wsum = 0.f;
    for (int yy = ylo; yy <= yhi; ++yy) {
        float w = 1.0f - fabsf((float)yy - centre) * 0.1f;
        float v = bf2f(f0c[(((size_t)b * 300 + yy) * 300 + x) * 64 + c]);
        float t = fmaxf((v - mu) * rs * gg + bb, 0.f);
        acc = fmaf(w, t, acc);
        wsum += w;
    }
    vtmp[idx] = acc / wsum;
}

// horizontal pass: 300 -> 30 cols; emit B = nl30, A = pooled*nl30, layout [b][sp][c]
__global__ __launch_bounds__(256) void k_horiz(
    const float* __restrict__ vtmp, const float* __restrict__ pooled,
    float* __restrict__ A, float* __restrict__ Bm)
{
    const int idx = blockIdx.x * 256 + threadIdx.x;
    if (idx >= 4 * 30 * 30 * 64) return;
    const int c = idx & 63;
    int rest = idx >> 6;
    const int i = rest % 30; rest /= 30;
    const int j = rest % 30;
    const int b = rest / 30;
    const int xlo = max(0, 10 * i - 5), xhi = min(299, 10 * i + 14);
    const float centre = (float)(10 * i) + 4.5f;
    float acc = 0.f, wsum = 0.f;
    for (int xx = xlo; xx <= xhi; ++xx) {
        float w = 1.0f - fabsf((float)xx - centre) * 0.1f;
        acc = fmaf(w, vtmp[(((size_t)b * 30 + j) * 300 + xx) * 64 + c], acc);
        wsum += w;
    }
    float nl30 = acc / wsum;
    Bm[idx] = nl30;
    A[idx] = pooled[b * 900 + j * 30 + i] * nl30;
}

// nl[b,i] = max_j sum_c A[b,i,c]*B[b,j,c]  (atomicMax on encoded key)
__global__ __launch_bounds__(256) void k_nl(
    const float* __restrict__ A, const float* __restrict__ Bm, uint* __restrict__ nlkey)
{
    __shared__ float lb[75 * 64];
    const int b = blockIdx.z;
    const int j0 = blockIdx.x * 75;
    const int i1 = blockIdx.y * 512 + threadIdx.x;
    const int i2 = i1 + 256;
    for (int s = threadIdx.x; s < 75 * 64; s += 256)
        lb[s] = Bm[(size_t)(b * 900 + j0) * 64 + s];
    __syncthreads();
    const bool v1 = i1 < 900, v2 = i2 < 900;
    float a1[64], a2[64];
    const float* A1 = A + (size_t)(b * 900 + i1) * 64;
    const float* A2 = A + (size_t)(b * 900 + i2) * 64;
#pragma unroll
    for (int c = 0; c < 64; ++c) { a1[c] = v1 ? A1[c] : 0.f; a2[c] = v2 ? A2[c] : 0.f; }
    float m1 = -INFINITY, m2 = -INFINITY;
    for (int jj = 0; jj < 75; ++jj) {
        const float* bp = lb + jj * 64;
        float d1 = 0.f, d2 = 0.f;
#pragma unroll
        for (int c = 0; c < 64; ++c) { float bv = bp[c]; d1 = fmaf(a1[c], bv, d1); d2 = fmaf(a2[c], bv, d2); }
        m1 = fmaxf(m1, d1); m2 = fmaxf(m2, d2);
    }
    if (v1) atomicMax(&nlkey[b * 900 + i1], enc(m1));
    if (v2) atomicMax(&nlkey[b * 900 + i2], enc(m2));
}

// base2 = upsample(nl,30->300) * base; sup = 1x1 conv of base2
__global__ __launch_bounds__(256) void k_base2_sup(
    const float* __restrict__ basep, const uint* __restrict__ nlkey,
    const float* __restrict__ wsup, const float* __restrict__ bsup,
    float* __restrict__ out_b2, float* __restrict__ out_sup)
{
    const int b = blockIdx.y;
    const int idx = blockIdx.x * 256 + threadIdx.x;
    if (idx >= 22500) return;
    const int p4 = idx * 4;
    const int yy = p4 / 300, xx = p4 - yy * 300;
    const uint* nk = nlkey + b * 900;
    float cyf = ((float)yy + 0.5f) * 0.1f - 0.5f;
    int iy = (int)floorf(cyf);
    float ay = cyf - (float)iy;
    int jy0 = min(max(iy, 0), 29), jy1 = min(iy + 1, 29);
    float e[4];
#pragma unroll
    for (int k = 0; k < 4; ++k) {
        float cxf = ((float)(xx + k) + 0.5f) * 0.1f - 0.5f;
        int ix = (int)floorf(cxf);
        float ax = cxf - (float)ix;
        int jx0 = min(max(ix, 0), 29), jx1 = min(ix + 1, 29);
        float n00 = dec(nk[jy0 * 30 + jx0]), n01 = dec(nk[jy0 * 30 + jx1]);
        float n10 = dec(nk[jy1 * 30 + jx0]), n11 = dec(nk[jy1 * 30 + jx1]);
        e[k] = (1.f - ay) * ((1.f - ax) * n00 + ax * n01) + ay * ((1.f - ax) * n10 + ax * n11);
    }
    float4 sacc = make_float4(0.f, 0.f, 0.f, 0.f);
    for (int c = 0; c < 64; ++c) {
        size_t off = ((size_t)(b * 64 + c)) * HWp + p4;
        float4 v = *(const float4*)(basep + off);
        float4 t;
        t.x = v.x * e[0]; t.y = v.y * e[1]; t.z = v.z * e[2]; t.w = v.w * e[3];
        *(float4*)(out_b2 + off) = t;
        const float wc = wsup[c];
        sacc.x = fmaf(wc, t.x, sacc.x);
        sacc.y = fmaf(wc, t.y, sacc.y);
        sacc.z = fmaf(wc, t.z, sacc.z);
        sacc.w = fmaf(wc, t.w, sacc.w);
    }
    const float bz = bsup[0];
    float4 so;
    so.x = sacc.x + bz; so.y = sacc.y + bz; so.z = sacc.z + bz; so.w = sacc.w + bz;
    *(float4*)(out_sup + (size_t)b * HWp + p4) = so;
}

// ---------------------------------------------------------------------------
extern "C" void kernel_launch(void* const* d_in, const int* in_sizes, int n_in,
                              void* d_out, int out_size, void* d_ws, size_t ws_size,
                              hipStream_t stream)
{
    (void)in_sizes; (void)n_in; (void)out_size; (void)ws_size;
    const float* fdm     = (const float*)d_in[0];
    const float* x2      = (const float*)d_in[3];
    const float* x3      = (const float*)d_in[4];
    const float* x4      = (const float*)d_in[5];
    const float* fuse_W  = (const float*)d_in[6];
    const float* fuse_b  = (const float*)d_in[7];
    const float* fuse_g  = (const float*)d_in[8];
    const float* fuse_be = (const float*)d_in[9];
    const float* bcg_W   = (const float*)d_in[10];
    const float* bcg_b   = (const float*)d_in[11];
    const float* f0_W    = (const float*)d_in[12];
    const float* f0_b    = (const float*)d_in[13];
    const float* f0_g    = (const float*)d_in[14];
    const float* f0_be   = (const float*)d_in[15];
    const float* sup_W   = (const float*)d_in[16];
    const float* sup_b   = (const float*)d_in[17];

    // workspace layout (bytes)
    char* ws = (char*)d_ws;
    float*  basep    = (float*)ws;                                // 92,160,000 B
    ushort* f0c      = (ushort*)(ws + 92160000);                  // 46,080,000 B
    double* fusepart = (double*)(ws + 138240000);                 // 11,400 dbl (4 x 1425 x 2)
    double* f0part   = (double*)(ws + 138331200);                 // 11,400 dbl
    double* bcgpart  = (double*)(ws + 138422400);                 // 352 dbl
    float*  fext     = (float*)(ws + 138425216);
    float*  fstats   = fext;            // 8
    float*  f0stats  = fext + 8;        // 8
    float*  bcgmean  = fext + 16;       // 4
    float*  pooled   = fext + 32;       // 3600
    float*  Abuf     = fext + 4000;     // 230400
    float*  Bbuf     = fext + 234400;   // 230400
    uint*   nlkey    = (uint*)(fext + 464800); // 3600
    float*  vtmp     = (float*)(ws + 140320000);                  // 9,216,000 B
    // weight repacks overlap vtmp's region: consumed before k_vert writes vtmp
    ushort* Wsplit   = (ushort*)(ws + 140320000);                 // 442,368 B
    ushort* Wfrag    = (ushort*)(ws + 140800000);                 // 73,728 B

    float* o_fdm  = (float*)d_out;
    float* o_bcg  = o_fdm + 360000;
    float* o_b2   = o_fdm + 720000;
    float* o_sup  = o_fdm + 23760000;

    k_repack_fsplit<<<864, 256, 0, stream>>>(fuse_W, Wsplit);
    k_repack_f0<<<144, 256, 0, stream>>>(f0_W, Wfrag);
    k_fuse_mfma<<<dim3(19, 75, 4), 256, 0, stream>>>(x2, x3, x4, Wsplit, fuse_b, basep, fusepart);
    k_redstats<<<4, 64, 0, stream>>>(fusepart, 1425, 1.0 / 5760000.0, fstats);
    k_finalize<<<dim3(88, 4), 256, 0, stream>>>(basep, o_bcg, fuse_g, fuse_be, bcg_W, bcg_b, fstats, bcgpart);
    k_redmean<<<4, 64, 0, stream>>>(bcgpart, 88, 1.0 / 90000.0, bcgmean);
    k_maskpool<<<dim3(900, 4), 128, 0, stream>>>(fdm, o_bcg, bcgmean, o_fdm, pooled);
    k_fuse0_conv<<<dim3(19, 75, 4), 256, 0, stream>>>(basep, Wfrag, f0_b, f0c, f0part);
    k_redstats<<<4, 64, 0, stream>>>(f0part, 1425, 1.0 / 5760000.0, f0stats);
    k_vert<<<9000, 256, 0, stream>>>(f0c, f0_g, f0_be, f0stats, vtmp);
    k_horiz<<<900, 256, 0, stream>>>(vtmp, pooled, Abuf, Bbuf);
    hipMemsetAsync(nlkey, 0, 3600 * sizeof(uint), stream);
    k_nl<<<dim3(12, 2, 4), 256, 0, stream>>>(Abuf, Bbuf, nlkey);
    k_base2_sup<<<dim3(88, 4), 256, 0, stream>>>(basep, nlkey, sup_W, sup_b, o_b2, o_sup);
}

// Round 7
// 901.454 us; speedup vs baseline: 2.1574x; 1.0012x over previous
//
#include <hip/hip_runtime.h>
#include <math.h>

typedef unsigned int uint;
typedef unsigned short ushort;
typedef __attribute__((ext_vector_type(8))) short bf16x8;
typedef __attribute__((ext_vector_type(8))) _Float16 f16x8;
typedef __attribute__((ext_vector_type(4))) float f32x4;

#define HWp 90000

__device__ __forceinline__ float bf2f(ushort u) { return __uint_as_float(((uint)u) << 16); }
__device__ __forceinline__ ushort f2bf(float f) {
    uint u = __float_as_uint(f);
    uint r = (u + 0x7FFFu + ((u >> 16) & 1u)) >> 16;
    return (ushort)r;
}
__device__ __forceinline__ ushort f2h(float f) { _Float16 h = (_Float16)f; ushort u; __builtin_memcpy(&u, &h, 2); return u; }
__device__ __forceinline__ float h2f(ushort u) { _Float16 h; __builtin_memcpy(&h, &u, 2); return (float)h; }
__device__ __forceinline__ uint enc(float f) {
    uint u = __float_as_uint(f);
    return (u & 0x80000000u) ? ~u : (u | 0x80000000u);
}
__device__ __forceinline__ float dec(uint k) {
    uint u = (k & 0x80000000u) ? (k ^ 0x80000000u) : ~k;
    return __uint_as_float(u);
}

// ---------------------------------------------------------------------------
// Wsplit[wsel][ck][tap][n][lane][j] f16 <- fuse_W [oc][c][tap] * 256, hi/lo split
__global__ __launch_bounds__(256) void k_repack_fsplit(const float* __restrict__ Wf, ushort* __restrict__ Ws) {
    int i = blockIdx.x * 256 + threadIdx.x;       // 2*6*9*4*64*8 = 221184
    if (i >= 221184) return;
    int j = i & 7; int l = (i >> 3) & 63; int n = (i >> 9) & 3;
    int r = i >> 11; int tap = r % 9; int ck = (r / 9) % 6; int wsel = r / 54;
    int oc = n * 16 + (l & 15);
    int c  = ck * 32 + ((l >> 4) << 3) + j;
    float w = Wf[(size_t)oc * 1728 + c * 9 + tap] * 256.0f;
    ushort h = f2h(w);
    Ws[i] = wsel ? f2h(w - h2f(h)) : h;
}
// Wfrag[tap][kstep][octile][lane][j] bf16 <- fuse0_W [oc][c][tap]
__global__ __launch_bounds__(256) void k_repack_f0(const float* __restrict__ W0, ushort* __restrict__ Wfrag) {
    int i = blockIdx.x * 256 + threadIdx.x;       // 36864
    if (i >= 36864) return;
    int j = i & 7; int l = (i >> 3) & 63; int octile = (i >> 9) & 3;
    int kstep = (i >> 11) & 1; int tap = i >> 12;
    int oc = octile * 16 + (l & 15);
    int c  = kstep * 32 + (l >> 4) * 8 + j;
    Wfrag[i] = f2bf(W0[(size_t)oc * 576 + c * 9 + tap]);
}

// ---------------------------------------------------------------------------
// k_resize: precompute bilinear-resized cat(x2,x3,x4) at 300x300, scaled x256,
// split to f16 hi/lo, packed (hi | lo<<16), layout [b][y][x][192].
// Block: one row y, 64 x, 192 ch. LDS transpose for fully coalesced writes.
// ---------------------------------------------------------------------------
__global__ __launch_bounds__(256) void k_resize(
    const float* __restrict__ x2, const float* __restrict__ x3, const float* __restrict__ x4,
    uint* __restrict__ rsz)
{
    __shared__ uint lds[192 * 65];
    const int tid = threadIdx.x;
    const int x0 = blockIdx.x * 64;
    const int y  = blockIdx.y;
    const int b  = blockIdx.z;
    // per-level vertical coords
    int ry0[3], ry1[3]; float rwy[3];
#pragma unroll
    for (int lev = 0; lev < 3; ++lev) {
        int n = (lev == 0) ? 75 : (lev == 1 ? 38 : 19);
        float scale = (float)n * (1.0f / 300.0f);
        float fy = ((float)y + 0.5f) * scale - 0.5f;
        float fl = floorf(fy); int iy = (int)fl;
        rwy[lev] = fy - fl;
        ry0[lev] = min(max(iy, 0), n - 1) * n;
        ry1[lev] = min(iy + 1, n - 1) * n;
    }
    for (int e = tid; e < 12288; e += 256) {
        int x = e & 63, ch = e >> 6;
        int gx = x0 + x;
        uint pk = 0;
        if (gx < 300) {
            int lev = ch >> 6, c = ch & 63;
            int n = (lev == 0) ? 75 : (lev == 1 ? 38 : 19);
            float scale = (float)n * (1.0f / 300.0f);
            const float* src = (lev == 0) ? x2 : (lev == 1 ? x3 : x4);
            const float* sp = src + (size_t)(b * 64 + c) * n * n;
            float fx = ((float)gx + 0.5f) * scale - 0.5f;
            float fl = floorf(fx); int ix = (int)fl; float ax = fx - fl;
            int c0 = min(max(ix, 0), n - 1), c1 = min(ix + 1, n - 1);
            float fy = rwy[lev];
            float v00 = sp[ry0[lev] + c0], v01 = sp[ry0[lev] + c1];
            float v10 = sp[ry1[lev] + c0], v11 = sp[ry1[lev] + c1];
            float a = ((1.f - fy) * ((1.f - ax) * v00 + ax * v01)
                     + fy * ((1.f - ax) * v10 + ax * v11)) * 256.0f;
            ushort hi = f2h(a);
            ushort lo = f2h(a - h2f(hi));
            pk = (uint)hi | ((uint)lo << 16);
        }
        lds[ch * 65 + x] = pk;
    }
    __syncthreads();
    uint* op = rsz + ((size_t)(b * 300 + y) * 300 + x0) * 192;
    for (int e = tid; e < 12288; e += 256) {
        int ch = e % 192, x = e / 192;
        if (x0 + x < 300) op[(size_t)x * 192 + ch] = lds[ch * 65 + x];
    }
}

// ---------------------------------------------------------------------------
// k_fuse_mfma_fast: conv3x3(rsz, 192->64) + bias via f16x2 split MFMA.
// Staging = coalesced packed loads; LDS [108 px][144 B]: hi ch*2 @0..63, lo @64..127.
// ---------------------------------------------------------------------------
__global__ __launch_bounds__(256, 4) void k_fuse_mfma_fast(
    const uint* __restrict__ rsz, const ushort* __restrict__ Ws, const float* __restrict__ bfv,
    float* __restrict__ preb, double* __restrict__ part)
{
    __shared__ char lds_a[108 * 144];
    __shared__ double red[8];
    const int tid = threadIdx.x;
    const int lane = tid & 63, w = tid >> 6;
    const int bz = blockIdx.z;
    const int y0 = blockIdx.y * 4;
    const int x0 = blockIdx.x * 16;
    const int mg = lane >> 4, mr = lane & 15;

    f32x4 acc[4];
#pragma unroll
    for (int ot = 0; ot < 4; ++ot) acc[ot] = f32x4{0.f, 0.f, 0.f, 0.f};

    for (int ck = 0; ck < 6; ++ck) {
        // stage 108 px x 32 ch (16 ch-pairs)
        for (int e = tid; e < 1728; e += 256) {
            int k = e & 15, px = e >> 4;
            int hy = px / 18, hx = px - hy * 18;
            int gy = y0 + hy - 1, gx = x0 + hx - 1;
            uint hiw = 0, low = 0;
            if ((uint)gy < 300u && (uint)gx < 300u) {
                const uint* p = rsz + ((size_t)(bz * 300 + gy) * 300 + gx) * 192 + ck * 32 + k * 2;
                uint2 v = *(const uint2*)p;
                hiw = (v.x & 0xffffu) | (v.y << 16);
                low = (v.x >> 16) | (v.y & 0xffff0000u);
            }
            *(uint*)(lds_a + px * 144 + k * 4) = hiw;
            *(uint*)(lds_a + px * 144 + 64 + k * 4) = low;
        }
        __syncthreads();
#pragma unroll
        for (int tap = 0; tap < 9; ++tap) {
            const int p = (w + tap / 3) * 18 + (mr + tap % 3);
            const char* ap = lds_a + p * 144 + mg * 16;
            f16x8 ah = *(const f16x8*)ap;
            f16x8 al = *(const f16x8*)(ap + 64);
            const ushort* wh = Ws + ((size_t)(ck * 9 + tap)) * 2048 + lane * 8;
            const ushort* wl = wh + 54 * 2048;
#pragma unroll
            for (int ot = 0; ot < 4; ++ot) {
                f16x8 bh = *(const f16x8*)(wh + ot * 512);
                acc[ot] = __builtin_amdgcn_mfma_f32_16x16x32_f16(ah, bh, acc[ot], 0, 0, 0);
                acc[ot] = __builtin_amdgcn_mfma_f32_16x16x32_f16(al, bh, acc[ot], 0, 0, 0);
                f16x8 bl = *(const f16x8*)(wl + ot * 512);
                acc[ot] = __builtin_amdgcn_mfma_f32_16x16x32_f16(ah, bl, acc[ot], 0, 0, 0);
            }
        }
        __syncthreads();
    }
    const int yo = y0 + w;
    float s = 0.f, ss = 0.f;
#pragma unroll
    for (int ot = 0; ot < 4; ++ot) {
        int oc = ot * 16 + mr;
        float bia = bfv[oc];
#pragma unroll
        for (int i2 = 0; i2 < 4; ++i2) {
            int xo = x0 + mg * 4 + i2;
            if (xo < 300) {
                float t = acc[ot][i2] * (1.0f / 65536.0f) + bia;
                preb[(size_t)(bz * 64 + oc) * HWp + yo * 300 + xo] = t;
                s += t; ss += t * t;
            }
        }
    }
    double ds = s, dss = ss;
    for (int off = 32; off; off >>= 1) { ds += __shfl_down(ds, off); dss += __shfl_down(dss, off); }
    if (lane == 0) { red[w * 2] = ds; red[w * 2 + 1] = dss; }
    __syncthreads();
    if (tid == 0) {
        double S = red[0] + red[2] + red[4] + red[6];
        double SS = red[1] + red[3] + red[5] + red[7];
        int blin = (bz * 75 + blockIdx.y) * 19 + blockIdx.x;
        part[2 * blin] = S; part[2 * blin + 1] = SS;
    }
}

// ---------------------------------------------------------------------------
// k_fuse_mfma_bilin: round-6 fallback (in-kernel bilinear) for small ws_size.
// ---------------------------------------------------------------------------
__global__ __launch_bounds__(256, 4) void k_fuse_mfma_bilin(
    const float* __restrict__ x2, const float* __restrict__ x3, const float* __restrict__ x4,
    const ushort* __restrict__ Ws, const float* __restrict__ bfv,
    float* __restrict__ preb, double* __restrict__ part)
{
    __shared__ char lds_a[108 * 144];
    __shared__ int   t_y0[18], t_y1[18];
    __shared__ float t_wy[18];
    __shared__ int   t_x0[54], t_x1[54];
    __shared__ float t_wx[54];
    __shared__ double red[8];
    const int tid = threadIdx.x;
    const int lane = tid & 63, w = tid >> 6;
    const int bz = blockIdx.z;
    const int y0 = blockIdx.y * 4;
    const int x0 = blockIdx.x * 16;
    const int mg = lane >> 4, mr = lane & 15;

    for (int i = tid; i < 72; i += 256) {
        int lev = i / 24, k = i - lev * 24;
        int n = (lev == 0) ? 75 : (lev == 1 ? 38 : 19);
        float scale = (float)n * (1.0f / 300.0f);
        if (k < 6) {
            int gy = y0 + k - 1;
            float fy = ((float)gy + 0.5f) * scale - 0.5f;
            float fl = floorf(fy); int iy = (int)fl; float ay = fy - fl;
            t_y0[lev * 6 + k] = min(max(iy, 0), n - 1) * n;
            t_y1[lev * 6 + k] = min(iy + 1, n - 1) * n;
            t_wy[lev * 6 + k] = ay;
        } else {
            int j = k - 6;
            int gx = x0 + j - 1;
            float fx = ((float)gx + 0.5f) * scale - 0.5f;
            float fl = floorf(fx); int ix = (int)fl; float ax = fx - fl;
            t_x0[lev * 18 + j] = min(max(ix, 0), n - 1);
            t_x1[lev * 18 + j] = min(ix + 1, n - 1);
            t_wx[lev * 18 + j] = ax;
        }
    }
    __syncthreads();

    f32x4 acc[4];
#pragma unroll
    for (int ot = 0; ot < 4; ++ot) acc[ot] = f32x4{0.f, 0.f, 0.f, 0.f};

    for (int ck = 0; ck < 6; ++ck) {
        const int lev = ck >> 1;
        const float* src = (lev == 0) ? x2 : (lev == 1 ? x3 : x4);
        const int n = (lev == 0) ? 75 : (lev == 1 ? 38 : 19);
        const float* plane0 = src + (size_t)(bz * 64 + (ck & 1) * 32) * n * n;
        for (int e = tid; e < 3456; e += 256) {
            int ch = e / 108;
            int px = e - ch * 108;
            int hy = px / 18, hx = px - hy * 18;
            int gy = y0 + hy - 1, gx = x0 + hx - 1;
            float a = 0.f;
            if ((uint)gy < 300u && (uint)gx < 300u) {
                const float* sp = plane0 + (size_t)ch * n * n;
                int r0 = t_y0[lev * 6 + hy], r1 = t_y1[lev * 6 + hy]; float fy = t_wy[lev * 6 + hy];
                int c0 = t_x0[lev * 18 + hx], c1 = t_x1[lev * 18 + hx]; float fx = t_wx[lev * 18 + hx];
                float v00 = sp[r0 + c0], v01 = sp[r0 + c1];
                float v10 = sp[r1 + c0], v11 = sp[r1 + c1];
                a = ((1.f - fy) * ((1.f - fx) * v00 + fx * v01)
                   + fy * ((1.f - fx) * v10 + fx * v11)) * 256.0f;
            }
            ushort hi = f2h(a);
            ushort lo = f2h(a - h2f(hi));
            char* p = lds_a + px * 144 + ch * 2;
            *(ushort*)p = hi;
            *(ushort*)(p + 64) = lo;
        }
        __syncthreads();
#pragma unroll
        for (int tap = 0; tap < 9; ++tap) {
            const int p = (w + tap / 3) * 18 + (mr + tap % 3);
            const char* ap = lds_a + p * 144 + mg * 16;
            f16x8 ah = *(const f16x8*)ap;
            f16x8 al = *(const f16x8*)(ap + 64);
            const ushort* wh = Ws + ((size_t)(ck * 9 + tap)) * 2048 + lane * 8;
            const ushort* wl = wh + 54 * 2048;
#pragma unroll
            for (int ot = 0; ot < 4; ++ot) {
                f16x8 bh = *(const f16x8*)(wh + ot * 512);
                acc[ot] = __builtin_amdgcn_mfma_f32_16x16x32_f16(ah, bh, acc[ot], 0, 0, 0);
                acc[ot] = __builtin_amdgcn_mfma_f32_16x16x32_f16(al, bh, acc[ot], 0, 0, 0);
                f16x8 bl = *(const f16x8*)(wl + ot * 512);
                acc[ot] = __builtin_amdgcn_mfma_f32_16x16x32_f16(ah, bl, acc[ot], 0, 0, 0);
            }
        }
        __syncthreads();
    }
    const int yo = y0 + w;
    float s = 0.f, ss = 0.f;
#pragma unroll
    for (int ot = 0; ot < 4; ++ot) {
        int oc = ot * 16 + mr;
        float bia = bfv[oc];
#pragma unroll
        for (int i2 = 0; i2 < 4; ++i2) {
            int xo = x0 + mg * 4 + i2;
            if (xo < 300) {
                float t = acc[ot][i2] * (1.0f / 65536.0f) + bia;
                preb[(size_t)(bz * 64 + oc) * HWp + yo * 300 + xo] = t;
                s += t; ss += t * t;
            }
        }
    }
    double ds = s, dss = ss;
    for (int off = 32; off; off >>= 1) { ds += __shfl_down(ds, off); dss += __shfl_down(dss, off); }
    if (lane == 0) { red[w * 2] = ds; red[w * 2 + 1] = dss; }
    __syncthreads();
    if (tid == 0) {
        double S = red[0] + red[2] + red[4] + red[6];
        double SS = red[1] + red[3] + red[5] + red[7];
        int blin = (bz * 75 + blockIdx.y) * 19 + blockIdx.x;
        part[2 * blin] = S; part[2 * blin + 1] = SS;
    }
}

// ---------------------------------------------------------------------------
// k_fuse0_conv (MFMA): conv3x3(base, 64->64) + bias -> bf16 [b][y][x][c] + stats
// ---------------------------------------------------------------------------
__global__ __launch_bounds__(256, 4) void k_fuse0_conv(
    const float* __restrict__ basep, const ushort* __restrict__ Wfrag,
    const float* __restrict__ b0, ushort* __restrict__ f0c, double* __restrict__ part)
{
    __shared__ ushort lds_x[108 * 64];
    __shared__ double red[8];
    const int tid = threadIdx.x;
    const int lane = tid & 63, w = tid >> 6;
    const int bz = blockIdx.z;
    const int y0 = blockIdx.y * 4;
    const int x0 = blockIdx.x * 16;

    for (int i = tid; i < 6912; i += 256) {
        int c = i / 108, p = i - c * 108;
        int hy = p / 18, hx = p - hy * 18;
        int gy = y0 + hy - 1, gx = x0 + hx - 1;
        float v = 0.f;
        if ((uint)gy < 300u && (uint)gx < 300u)
            v = basep[(size_t)(bz * 64 + c) * HWp + gy * 300 + gx];
        int byteoff = p * 128 + ((c * 2) ^ ((p & 7) << 4));
        *(ushort*)((char*)lds_x + byteoff) = f2bf(v);
    }
    __syncthreads();

    f32x4 acc[4];
#pragma unroll
    for (int ot = 0; ot < 4; ++ot) acc[ot] = f32x4{0.f, 0.f, 0.f, 0.f};
    const int mg = lane >> 4;
    const int mr = lane & 15;
#pragma unroll
    for (int tap = 0; tap < 9; ++tap) {
        const int dy = tap / 3, dx = tap % 3;
        const int p = (w + dy) * 18 + (mr + dx);
#pragma unroll
        for (int ks = 0; ks < 2; ++ks) {
            int slot = ks * 4 + mg;
            int byteoff = p * 128 + ((slot * 16) ^ ((p & 7) << 4));
            bf16x8 a = *(bf16x8*)((char*)lds_x + byteoff);
            const ushort* wp = Wfrag + (((size_t)(tap * 2 + ks) * 4) * 64 + lane) * 8;
#pragma unroll
            for (int ot = 0; ot < 4; ++ot) {
                bf16x8 bv = *(const bf16x8*)(wp + ot * 512);
                acc[ot] = __builtin_amdgcn_mfma_f32_16x16x32_bf16(a, bv, acc[ot], 0, 0, 0);
            }
        }
    }
    const int yo = y0 + w;
    float s = 0.f, ss = 0.f;
#pragma unroll
    for (int ot = 0; ot < 4; ++ot) {
        int oc = ot * 16 + mr;
        float bia = b0[oc];
#pragma unroll
        for (int i2 = 0; i2 < 4; ++i2) {
            int xo = x0 + mg * 4 + i2;
            if (xo < 300) {
                float t = acc[ot][i2] + bia;
                f0c[((size_t)(bz * 300 + yo) * 300 + xo) * 64 + oc] = f2bf(t);
                s += t; ss += t * t;
            }
        }
    }
    double ds = s, dss = ss;
    for (int off = 32; off; off >>= 1) { ds += __shfl_down(ds, off); dss += __shfl_down(dss, off); }
    if (lane == 0) { red[w * 2] = ds; red[w * 2 + 1] = dss; }
    __syncthreads();
    if (tid == 0) {
        double S = red[0] + red[2] + red[4] + red[6];
        double SS = red[1] + red[3] + red[5] + red[7];
        int blin = (bz * 75 + blockIdx.y) * 19 + blockIdx.x;
        part[2 * blin] = S; part[2 * blin + 1] = SS;
    }
}

// reduce (sum,sumsq) partials -> (mu, rsqrt(var+eps))
__global__ __launch_bounds__(64) void k_redstats(const double* __restrict__ part, int cnt,
                                                 double invN, float* __restrict__ stats)
{
    int b = blockIdx.x, t = threadIdx.x;
    double s = 0, ss = 0;
    for (int i = t; i < cnt; i += 64) { s += part[2 * (b * cnt + i)]; ss += part[2 * (b * cnt + i) + 1]; }
    for (int off = 32; off; off >>= 1) { s += __shfl_down(s, off); ss += __shfl_down(ss, off); }
    if (t == 0) {
        double mu = s * invN;
        double var = ss * invN - mu * mu;
        stats[2 * b] = (float)mu;
        stats[2 * b + 1] = (float)(1.0 / sqrt(var + 1e-5));
    }
}

__global__ __launch_bounds__(64) void k_redmean(const double* __restrict__ part, int cnt,
                                                double invN, float* __restrict__ out)
{
    int b = blockIdx.x, t = threadIdx.x;
    double s = 0;
    for (int i = t; i < cnt; i += 64) s += part[b * cnt + i];
    for (int off = 32; off; off >>= 1) s += __shfl_down(s, off);
    if (t == 0) out[b] = (float)(s * invN);
}

// GN+ReLU in place (preb -> base) + bcg 1x1 conv + sigmoid + per-block bcg sums
__global__ __launch_bounds__(256) void k_finalize(
    float* __restrict__ basep, float* __restrict__ bcg_out,
    const float* __restrict__ fg, const float* __restrict__ fbe,
    const float* __restrict__ wb, const float* __restrict__ bb,
    const float* __restrict__ fstats, double* __restrict__ bcgpart)
{
    const int b = blockIdx.y;
    const int idx = blockIdx.x * 256 + threadIdx.x;
    float lsum = 0.f;
    if (idx < 22500) {
        const int p4 = idx * 4;
        const float mu = fstats[b * 2], rs = fstats[b * 2 + 1];
        float4 acc = make_float4(0.f, 0.f, 0.f, 0.f);
        for (int c = 0; c < 64; ++c) {
            float* ptr = basep + ((size_t)(b * 64 + c)) * HWp + p4;
            float4 v = *(float4*)ptr;
            const float g = fg[c], be = fbe[c];
            float4 t;
            t.x = fmaxf((v.x - mu) * rs * g + be, 0.f);
            t.y = fmaxf((v.y - mu) * rs * g + be, 0.f);
            t.z = fmaxf((v.z - mu) * rs * g + be, 0.f);
            t.w = fmaxf((v.w - mu) * rs * g + be, 0.f);
            *(float4*)ptr = t;
            const float wc = wb[c];
            acc.x = fmaf(wc, t.x, acc.x);
            acc.y = fmaf(wc, t.y, acc.y);
            acc.z = fmaf(wc, t.z, acc.z);
            acc.w = fmaf(wc, t.w, acc.w);
        }
        const float bz = bb[0];
        float4 sg;
        sg.x = 1.f / (1.f + expf(-(acc.x + bz)));
        sg.y = 1.f / (1.f + expf(-(acc.y + bz)));
        sg.z = 1.f / (1.f + expf(-(acc.z + bz)));
        sg.w = 1.f / (1.f + expf(-(acc.w + bz)));
        *(float4*)(bcg_out + (size_t)b * HWp + p4) = sg;
        lsum = sg.x + sg.y + sg.z + sg.w;
    }
    double d = lsum;
    for (int off = 32; off; off >>= 1) d += __shfl_down(d, off);
    __shared__ double rr[4];
    int wid = threadIdx.x >> 6, lane = threadIdx.x & 63;
    if (lane == 0) rr[wid] = d;
    __syncthreads();
    if (threadIdx.x == 0) bcgpart[b * 88 + blockIdx.x] = rr[0] + rr[1] + rr[2] + rr[3];
}

// fdm_m = fdm * (bcg > mean); pooled = 10x10 window max of fdm_m
__global__ __launch_bounds__(128) void k_maskpool(
    const float* __restrict__ fdm, const float* __restrict__ bcg,
    const float* __restrict__ bcgmean, float* __restrict__ fdm_m, float* __restrict__ pooled)
{
    const int cell = blockIdx.x;
    const int b = blockIdx.y;
    const int t = threadIdx.x;
    const int cy = cell / 30, cx = cell - cy * 30;
    float m = -INFINITY;
    if (t < 100) {
        int yy = cy * 10 + t / 10, xx = cx * 10 + t % 10;
        size_t p = (size_t)b * HWp + yy * 300 + xx;
        float v = (bcg[p] > bcgmean[b]) ? fdm[p] : 0.f;
        fdm_m[p] = v;
        m = v;
    }
    for (int off = 32; off; off >>= 1) m = fmaxf(m, __shfl_down(m, off));
    __shared__ float rr[2];
    if ((t & 63) == 0) rr[t >> 6] = m;
    __syncthreads();
    if (t == 0) pooled[b * 900 + cell] = fmaxf(rr[0], rr[1]);
}

// vertical antialiased triangle downsample of relu(GN(f0conv)) : 300 -> 30 rows
__global__ __launch_bounds__(256) void k_vert(
    const ushort* __restrict__ f0c, const float* __restrict__ g0, const float* __restrict__ be0,
    const float* __restrict__ f0stats, float* __restrict__ vtmp)
{
    const int idx = blockIdx.x * 256 + threadIdx.x;
    if (idx >= 4 * 30 * 300 * 64) return;
    const int c = idx & 63;
    int rest = idx >> 6;
    const int x = rest % 300; rest /= 300;
    const int j = rest % 30;
    const int b = rest / 30;
    const float mu = f0stats[2 * b], rs = f0stats[2 * b + 1];
    const float gg = g0[c], bb = be0[c];
    const int ylo = max(0, 10 * j - 5), yhi = min(299, 10 * j + 14);
    const float centre = (float)(10 * j) + 4.5f;
    float acc = 0.f, wsum = 0.f;
    for (int yy = ylo; yy <= yhi; ++yy) {
        float w = 1.0f - fabsf((float)yy - centre) * 0.1f;
        float v = bf2f(f0c[(((size_t)b * 300 + yy) * 300 + x) * 64 + c]);
        float t = fmaxf((v - mu) * rs * gg + bb, 0.f);
        acc = fmaf(w, t, acc);
        wsum += w;
    }
    vtmp[idx] = acc / wsum;
}

// horizontal pass: 300 -> 30 cols; emit B = nl30, A = pooled*nl30, layout [b][sp][c]
__global__ __launch_bounds__(256) void k_horiz(
    const float* __restrict__ vtmp, const float* __restrict__ pooled,
    float* __restrict__ A, float* __restrict__ Bm)
{
    const int idx = blockIdx.x * 256 + threadIdx.x;
    if (idx >= 4 * 30 * 30 * 64) return;
    const int c = idx & 63;
    int rest = idx >> 6;
    const int i = rest % 30; rest /= 30;
    const int j = rest % 30;
    const int b = rest / 30;
    const int xlo = max(0, 10 * i - 5), xhi = min(299, 10 * i + 14);
    const float centre = (float)(10 * i) + 4.5f;
    float acc = 0.f, wsum = 0.f;
    for (int xx = xlo; xx <= xhi; ++xx) {
        float w = 1.0f - fabsf((float)xx - centre) * 0.1f;
        acc = fmaf(w, vtmp[(((size_t)b * 30 + j) * 300 + xx) * 64 + c], acc);
        wsum += w;
    }
    float nl30 = acc / wsum;
    Bm[idx] = nl30;
    A[idx] = pooled[b * 900 + j * 30 + i] * nl30;
}

// nl[b,i] = max_j sum_c A[b,i,c]*B[b,j,c]  (atomicMax on encoded key)
__global__ __launch_bounds__(256) void k_nl(
    const float* __restrict__ A, const float* __restrict__ Bm, uint* __restrict__ nlkey)
{
    __shared__ float lb[75 * 64];
    const int b = blockIdx.z;
    const int j0 = blockIdx.x * 75;
    const int i1 = blockIdx.y * 512 + threadIdx.x;
    const int i2 = i1 + 256;
    for (int s = threadIdx.x; s < 75 * 64; s += 256)
        lb[s] = Bm[(size_t)(b * 900 + j0) * 64 + s];
    __syncthreads();
    const bool v1 = i1 < 900, v2 = i2 < 900;
    float a1[64], a2[64];
    const float* A1 = A + (size_t)(b * 900 + i1) * 64;
    const float* A2 = A + (size_t)(b * 900 + i2) * 64;
#pragma unroll
    for (int c = 0; c < 64; ++c) { a1[c] = v1 ? A1[c] : 0.f; a2[c] = v2 ? A2[c] : 0.f; }
    float m1 = -INFINITY, m2 = -INFINITY;
    for (int jj = 0; jj < 75; ++jj) {
        const float* bp = lb + jj * 64;
        float d1 = 0.f, d2 = 0.f;
#pragma unroll
        for (int c = 0; c < 64; ++c) { float bv = bp[c]; d1 = fmaf(a1[c], bv, d1); d2 = fmaf(a2[c], bv, d2); }
        m1 = fmaxf(m1, d1); m2 = fmaxf(m2, d2);
    }
    if (v1) atomicMax(&nlkey[b * 900 + i1], enc(m1));
    if (v2) atomicMax(&nlkey[b * 900 + i2], enc(m2));
}

// base2 = upsample(nl,30->300) * base; sup = 1x1 conv of base2
__global__ __launch_bounds__(256) void k_base2_sup(
    const float* __restrict__ basep, const uint* __restrict__ nlkey,
    const float* __restrict__ wsup, const float* __restrict__ bsup,
    float* __restrict__ out_b2, float* __restrict__ out_sup)
{
    const int b = blockIdx.y;
    const int idx = blockIdx.x * 256 + threadIdx.x;
    if (idx >= 22500) return;
    const int p4 = idx * 4;
    const int yy = p4 / 300, xx = p4 - yy * 300;
    const uint* nk = nlkey + b * 900;
    float cyf = ((float)yy + 0.5f) * 0.1f - 0.5f;
    int iy = (int)floorf(cyf);
    float ay = cyf - (float)iy;
    int jy0 = min(max(iy, 0), 29), jy1 = min(iy + 1, 29);
    float e[4];
#pragma unroll
    for (int k = 0; k < 4; ++k) {
        float cxf = ((float)(xx + k) + 0.5f) * 0.1f - 0.5f;
        int ix = (int)floorf(cxf);
        float ax = cxf - (float)ix;
        int jx0 = min(max(ix, 0), 29), jx1 = min(ix + 1, 29);
        float n00 = dec(nk[jy0 * 30 + jx0]), n01 = dec(nk[jy0 * 30 + jx1]);
        float n10 = dec(nk[jy1 * 30 + jx0]), n11 = dec(nk[jy1 * 30 + jx1]);
        e[k] = (1.f - ay) * ((1.f - ax) * n00 + ax * n01) + ay * ((1.f - ax) * n10 + ax * n11);
    }
    float4 sacc = make_float4(0.f, 0.f, 0.f, 0.f);
    for (int c = 0; c < 64; ++c) {
        size_t off = ((size_t)(b * 64 + c)) * HWp + p4;
        float4 v = *(const float4*)(basep + off);
        float4 t;
        t.x = v.x * e[0]; t.y = v.y * e[1]; t.z = v.z * e[2]; t.w = v.w * e[3];
        *(float4*)(out_b2 + off) = t;
        const float wc = wsup[c];
        sacc.x = fmaf(wc, t.x, sacc.x);
        sacc.y = fmaf(wc, t.y, sacc.y);
        sacc.z = fmaf(wc, t.z, sacc.z);
        sacc.w = fmaf(wc, t.w, sacc.w);
    }
    const float bz = bsup[0];
    float4 so;
    so.x = sacc.x + bz; so.y = sacc.y + bz; so.z = sacc.z + bz; so.w = sacc.w + bz;
    *(float4*)(out_sup + (size_t)b * HWp + p4) = so;
}

// ---------------------------------------------------------------------------
extern "C" void kernel_launch(void* const* d_in, const int* in_sizes, int n_in,
                              void* d_out, int out_size, void* d_ws, size_t ws_size,
                              hipStream_t stream)
{
    (void)in_sizes; (void)n_in; (void)out_size;
    const float* fdm     = (const float*)d_in[0];
    const float* x2      = (const float*)d_in[3];
    const float* x3      = (const float*)d_in[4];
    const float* x4      = (const float*)d_in[5];
    const float* fuse_W  = (const float*)d_in[6];
    const float* fuse_b  = (const float*)d_in[7];
    const float* fuse_g  = (const float*)d_in[8];
    const float* fuse_be = (const float*)d_in[9];
    const float* bcg_W   = (const float*)d_in[10];
    const float* bcg_b   = (const float*)d_in[11];
    const float* f0_W    = (const float*)d_in[12];
    const float* f0_b    = (const float*)d_in[13];
    const float* f0_g    = (const float*)d_in[14];
    const float* f0_be   = (const float*)d_in[15];
    const float* sup_W   = (const float*)d_in[16];
    const float* sup_b   = (const float*)d_in[17];

    char* ws = (char*)d_ws;
    const bool big = ws_size >= (size_t)427000000;

    float* o_fdm  = (float*)d_out;
    float* o_bcg  = o_fdm + 360000;
    float* o_b2   = o_fdm + 720000;
    float* o_sup  = o_fdm + 23760000;

    float*  basep = (float*)ws;                       // 92,160,000 B
    ushort* f0c   = (ushort*)(ws + 92160000);         // 46,080,000 B

    double *fusepart, *f0part, *bcgpart; float* fext; float* vtmp;
    ushort *Wsplit, *Wfrag; uint* rsz = nullptr;
    if (big) {
        rsz      = (uint*)(ws + 138240000);           // 276,480,000 B
        fusepart = (double*)(ws + 414720000);         // 91,200 B
        f0part   = (double*)(ws + 414811200);         // 91,200 B
        bcgpart  = (double*)(ws + 414902400);         // 2,816 B
        fext     = (float*)(ws + 414905216);          // ~1.88 MB
        vtmp     = (float*)(ws + 416800000);          // 9,216,000 B
        Wsplit   = (ushort*)(ws + 426100000);         // 442,368 B
        Wfrag    = (ushort*)(ws + 426600000);         // 73,728 B
    } else {
        fusepart = (double*)(ws + 138240000);
        f0part   = (double*)(ws + 138331200);
        bcgpart  = (double*)(ws + 138422400);
        fext     = (float*)(ws + 138425216);
        vtmp     = (float*)(ws + 140320000);
        Wsplit   = (ushort*)(ws + 140320000);         // overlaps vtmp (consumed pre-k_vert)
        Wfrag    = (ushort*)(ws + 140800000);
    }
    float* fstats  = fext;
    float* f0stats = fext + 8;
    float* bcgmean = fext + 16;
    float* pooled  = fext + 32;
    float* Abuf    = fext + 4000;
    float* Bbuf    = fext + 234400;
    uint*  nlkey   = (uint*)(fext + 464800);

    k_repack_fsplit<<<864, 256, 0, stream>>>(fuse_W, Wsplit);
    k_repack_f0<<<144, 256, 0, stream>>>(f0_W, Wfrag);
    if (big) {
        k_resize<<<dim3(5, 300, 4), 256, 0, stream>>>(x2, x3, x4, rsz);
        k_fuse_mfma_fast<<<dim3(19, 75, 4), 256, 0, stream>>>(rsz, Wsplit, fuse_b, basep, fusepart);
    } else {
        k_fuse_mfma_bilin<<<dim3(19, 75, 4), 256, 0, stream>>>(x2, x3, x4, Wsplit, fuse_b, basep, fusepart);
    }
    k_redstats<<<4, 64, 0, stream>>>(fusepart, 1425, 1.0 / 5760000.0, fstats);
    k_finalize<<<dim3(88, 4), 256, 0, stream>>>(basep, o_bcg, fuse_g, fuse_be, bcg_W, bcg_b, fstats, bcgpart);
    k_redmean<<<4, 64, 0, stream>>>(bcgpart, 88, 1.0 / 90000.0, bcgmean);
    k_maskpool<<<dim3(900, 4), 128, 0, stream>>>(fdm, o_bcg, bcgmean, o_fdm, pooled);
    k_fuse0_conv<<<dim3(19, 75, 4), 256, 0, stream>>>(basep, Wfrag, f0_b, f0c, f0part);
    k_redstats<<<4, 64, 0, stream>>>(f0part, 1425, 1.0 / 5760000.0, f0stats);
    k_vert<<<9000, 256, 0, stream>>>(f0c, f0_g, f0_be, f0stats, vtmp);
    k_horiz<<<900, 256, 0, stream>>>(vtmp, pooled, Abuf, Bbuf);
    hipMemsetAsync(nlkey, 0, 3600 * sizeof(uint), stream);
    k_nl<<<dim3(12, 2, 4), 256, 0, stream>>>(Abuf, Bbuf, nlkey);
    k_base2_sup<<<dim3(88, 4), 256, 0, stream>>>(basep, nlkey, sup_W, sup_b, o_b2, o_sup);
}